// Round 7
// baseline (371.181 us; speedup 1.0000x reference)
//
#include <hip/hip_runtime.h>
#include <hip/hip_bf16.h>
#include <math.h>

typedef __hip_bfloat16 bf16;
typedef __attribute__((ext_vector_type(8))) short bf16x8;
typedef __attribute__((ext_vector_type(4))) float f32x4;

__device__ __forceinline__ float b2f(bf16 x) { return __bfloat162float(x); }
__device__ __forceinline__ float us2f(unsigned short u) {
    return __uint_as_float(((unsigned int)u) << 16);
}
__device__ __forceinline__ unsigned short f2us(float f) {
    bf16 t = __float2bfloat16(f);
    return *reinterpret_cast<unsigned short*>(&t);
}
__device__ __forceinline__ float scrub(float v) {
    return (v == v && fabsf(v) < 3.0e38f) ? v : 0.f;
}
__device__ __forceinline__ float to_float(float x) { return x; }
__device__ __forceinline__ float to_float(bf16 x) { return __bfloat162float(x); }
__device__ __forceinline__ void store_out(float* p, float v) { *p = v; }
__device__ __forceinline__ void store_out(bf16* p, float v) { *p = __float2bfloat16(v); }

// 16-lane-row suffix-sum step via DPP row_shr (rocPRIM reduce pattern).
// After ctrl = 0x111,0x112,0x114,0x118 applied in sequence, lane 15 of each
// 16-lane row holds the row sum.  Pure VALU: no LDS pipe, no lgkmcnt.
template <int CTRL>
__device__ __forceinline__ float dpp_shr_add(float x) {
    const int sh = __builtin_amdgcn_update_dpp(
        0, __float_as_int(x), CTRL, 0xF, 0xF, true);
    return x + __int_as_float(sh);
}

// async global->LDS, 16 B per lane; LDS dest = wave-uniform base + lane*16
// (m97 pattern: 517->874 TF on the GEMM ladder).
__device__ __forceinline__ void cp16(const void* g, void* l) {
    __builtin_amdgcn_global_load_lds(
        (const __attribute__((address_space(1))) unsigned int*)g,
        (__attribute__((address_space(3))) unsigned int*)l, 16, 0, 0);
}

// ---------------------------------------------------------------------------
// Fused: (a) convert the 17 weight tensors fp32 -> bf16 (skipping x, whose
// bf16 copy nothing reads), (b) LayerNorm-1 over x, reading fp32 gamma/beta
// directly from d_in so there is no dependency between the two halves.
// ---------------------------------------------------------------------------
struct Ptrs { const void* p[18]; };

__constant__ __device__ const long TOFF[19] = {
    0,         2097152,  2098176,  2099200,  6293504,  6301696,  6303744,
    6500352,   6631424,  6633472,  6666240,  6668288,  8765440,  8766464,
    8767488,   10864640, 10866688, 12963840, 12964864};

__global__ __launch_bounds__(256) void convert_ln1_kernel(
    Ptrs ptrs, unsigned short* __restrict__ dst, bf16* __restrict__ out)
{
    __shared__ float red[8];
    if (blockIdx.x < 5307) {
        const long g = 262144 + (long)blockIdx.x * 256 + threadIdx.x;
        if (g >= 1620608) return;            // 12,964,864 / 8
        const long e0 = g * 8;
        int t = 1;                           // e0 >= TOFF[1] always here
        #pragma unroll
        for (int i = 2; i < 18; ++i) t += (e0 >= TOFF[i]) ? 1 : 0;
        const long local = e0 - TOFF[t];
        const float4* ps = (const float4*)((const float*)ptrs.p[t] + local);
        const float4 a = ps[0], b = ps[1];
        ushort4 o0, o1;
        o0.x = f2us(a.x); o0.y = f2us(a.y); o0.z = f2us(a.z); o0.w = f2us(a.w);
        o1.x = f2us(b.x); o1.y = f2us(b.y); o1.z = f2us(b.z); o1.w = f2us(b.w);
        *(ushort4*)(dst + e0)     = o0;
        *(ushort4*)(dst + e0 + 4) = o1;
        return;
    }
    // ---- LN1: one block per row, 256 threads x 4 elems, fp32 weights ----
    const int row = blockIdx.x - 5307;
    const int tid = threadIdx.x;
    const float* xf = (const float*)ptrs.p[0];
    const float4 raw = ((const float4*)(xf + (long)row * 1024))[tid];
    float v[4] = {raw.x, raw.y, raw.z, raw.w};
    float s  = v[0] + v[1] + v[2] + v[3];
    float s2 = v[0]*v[0] + v[1]*v[1] + v[2]*v[2] + v[3]*v[3];
    #pragma unroll
    for (int o = 32; o > 0; o >>= 1) {
        s  += __shfl_xor(s, o);
        s2 += __shfl_xor(s2, o);
    }
    if ((tid & 63) == 0) { red[tid >> 6] = s; red[4 + (tid >> 6)] = s2; }
    __syncthreads();
    s  = red[0] + red[1] + red[2] + red[3];
    s2 = red[4] + red[5] + red[6] + red[7];
    const float mu  = s * (1.f / 1024.f);
    const float var = fmaxf(s2 * (1.f / 1024.f) - mu * mu, 0.f);
    const float rs  = rsqrtf(var + 1e-5f);
    const float4 w4 = ((const float4*)ptrs.p[1])[tid];
    const float4 b4 = ((const float4*)ptrs.p[2])[tid];
    ushort4 o;
    o.x = f2us((v[0] - mu) * rs * w4.x + b4.x);
    o.y = f2us((v[1] - mu) * rs * w4.y + b4.y);
    o.z = f2us((v[2] - mu) * rs * w4.z + b4.z);
    o.w = f2us((v[3] - mu) * rs * w4.w + b4.w);
    ((ushort4*)((unsigned short*)out + (long)row * 1024))[tid] = o;
}

// ---------------------------------------------------------------------------
// LayerNorm (generic, bf16 weights): used for LN2 over fp32 residual.
// ---------------------------------------------------------------------------
template <typename TIN>
__global__ __launch_bounds__(256) void ln_kernel(
    const TIN* __restrict__ in, const bf16* __restrict__ gw,
    const bf16* __restrict__ gb, bf16* __restrict__ out)
{
    const int row = blockIdx.x;
    const int tid = threadIdx.x;
    float v[4];
    if constexpr (sizeof(TIN) == 2) {
        ushort4 raw = ((const ushort4*)((const unsigned short*)in + (long)row * 1024))[tid];
        v[0] = us2f(raw.x); v[1] = us2f(raw.y); v[2] = us2f(raw.z); v[3] = us2f(raw.w);
    } else {
        float4 raw = ((const float4*)((const float*)in + (long)row * 1024))[tid];
        v[0] = raw.x; v[1] = raw.y; v[2] = raw.z; v[3] = raw.w;
    }
    float s  = v[0] + v[1] + v[2] + v[3];
    float s2 = v[0]*v[0] + v[1]*v[1] + v[2]*v[2] + v[3]*v[3];
    #pragma unroll
    for (int o = 32; o > 0; o >>= 1) {
        s  += __shfl_xor(s, o);
        s2 += __shfl_xor(s2, o);
    }
    __shared__ float red[8];
    if ((tid & 63) == 0) { red[tid >> 6] = s; red[4 + (tid >> 6)] = s2; }
    __syncthreads();
    s  = red[0] + red[1] + red[2] + red[3];
    s2 = red[4] + red[5] + red[6] + red[7];
    const float mu  = s * (1.f / 1024.f);
    const float var = fmaxf(s2 * (1.f / 1024.f) - mu * mu, 0.f);
    const float rs  = rsqrtf(var + 1e-5f);
    const int c0 = tid * 4;
    ushort4 o;
    o.x = f2us((v[0] - mu) * rs * b2f(gw[c0 + 0]) + b2f(gb[c0 + 0]));
    o.y = f2us((v[1] - mu) * rs * b2f(gw[c0 + 1]) + b2f(gb[c0 + 1]));
    o.z = f2us((v[2] - mu) * rs * b2f(gw[c0 + 2]) + b2f(gb[c0 + 2]));
    o.w = f2us((v[3] - mu) * rs * b2f(gw[c0 + 3]) + b2f(gb[c0 + 3]));
    ((ushort4*)((unsigned short*)out + (long)row * 1024))[tid] = o;
}

// ---------------------------------------------------------------------------
// GEMM v2 (m97-style): C[M,N] = act(A[M,K] @ Bw[N,K]^T + bias) + res.
// global_load_lds width-16 staging into unpadded [B][64] LDS; BK=64;
// 4 waves as 2x2, wave tile (BM/2)x(BN/2) of 16x16x32 MFMAs.
// NG: guard B rows against N (boundary is 8-row aligned).
// ---------------------------------------------------------------------------
template <int BM, int BN, int ACT, bool NG, typename TOUT, typename TRES>
__global__ __launch_bounds__(256) void gemm_as(
    const bf16* __restrict__ A, int lda,
    const bf16* __restrict__ Bw, int ldb,
    TOUT* __restrict__ C, int ldc,
    const bf16* __restrict__ bias,
    const TRES* __restrict__ res,
    int M, int N, int K)
{
    constexpr int AI = BM / 32;
    constexpr int BJ = BN / 32;
    __shared__ __align__(16) short As[BM * 64];
    __shared__ __align__(16) short Bs[BN * 64];
    const int tid  = threadIdx.x;
    const int lane = tid & 63;
    const int wv   = tid >> 6;
    const int m0 = blockIdx.y * BM;
    const int n0 = blockIdx.x * BN;
    const int wm = (wv >> 1) * (BM / 2);
    const int wn = (wv & 1) * (BN / 2);
    const int lr = lane & 15;
    const int lq = lane >> 4;
    const int grow = lane >> 3;         // row 0..7 within an 8-row group
    const int gcol = (lane & 7) * 8;    // 16B chunk (shorts)

    if (NG) {
        // one-time zero of OOB B rows (never re-written by skipped loads)
        const int z0 = (N - n0) * 64;
        uint4 z; z.x = z.y = z.z = z.w = 0;
        for (int s = z0 + tid * 8; s < BN * 64; s += 2048)
            *(uint4*)&Bs[s] = z;
    }

    f32x4 acc[AI][BJ] = {};

    for (int k0 = 0; k0 < K; k0 += 64) {
        #pragma unroll
        for (int g = 0; g < BM / 32; ++g) {
            const int gg = g * 4 + wv;   // wave-uniform 8-row group
            cp16(A + (long)(m0 + gg * 8 + grow) * lda + k0 + gcol, &As[gg * 512]);
        }
        #pragma unroll
        for (int g = 0; g < BN / 32; ++g) {
            const int gg = g * 4 + wv;
            if (!NG || n0 + gg * 8 < N)
                cp16(Bw + (long)(n0 + gg * 8 + grow) * ldb + k0 + gcol, &Bs[gg * 512]);
        }
        __syncthreads();   // compiler drains vmcnt before s_barrier (m97)

        #pragma unroll
        for (int kk = 0; kk < 2; ++kk) {
            bf16x8 af[AI], bfr[BJ];
            #pragma unroll
            for (int i = 0; i < AI; ++i)
                af[i] = *(const bf16x8*)&As[(wm + i * 16 + lr) * 64 + kk * 32 + lq * 8];
            #pragma unroll
            for (int j = 0; j < BJ; ++j)
                bfr[j] = *(const bf16x8*)&Bs[(wn + j * 16 + lr) * 64 + kk * 32 + lq * 8];
            #pragma unroll
            for (int i = 0; i < AI; ++i)
                #pragma unroll
                for (int j = 0; j < BJ; ++j)
                    acc[i][j] = __builtin_amdgcn_mfma_f32_16x16x32_bf16(
                        af[i], bfr[j], acc[i][j], 0, 0, 0);
        }
        __syncthreads();
    }

    // Epilogue.  C/D layout: col = lane&15, row = (lane>>4)*4 + reg.
    #pragma unroll
    for (int j = 0; j < BJ; ++j) {
        const int col = n0 + wn + j * 16 + lr;
        if (col >= N) continue;
        const float bv = bias ? b2f(bias[col]) : 0.f;
        #pragma unroll
        for (int i = 0; i < AI; ++i) {
            const int r0 = m0 + wm + i * 16 + lq * 4;
            #pragma unroll
            for (int r = 0; r < 4; ++r) {
                const long row = r0 + r;
                float v = acc[i][j][r] + bv;
                if (ACT == 1) v = 0.5f * v * (1.f + erff(v * 0.70710678118f));
                if (ACT == 2) v = (v > 20.f) ? v : __logf(1.f + __expf(v));
                if (res) v += to_float(res[row * (long)ldc + col]);
                store_out(&C[row * (long)ldc + col], scrub(v));
            }
        }
    }
}

// ---------------------------------------------------------------------------
// x_proj split-K: (M=2048, N=96, K=2048) with only (2,32) = 64 output tiles,
// the non-split kernel exposes 32 serial k-step latencies on 64 lonely
// blocks.  Split K into 4 ranges -> 256 blocks, fp32 partials, then reduce.
// ---------------------------------------------------------------------------
__global__ __launch_bounds__(256) void gemm_xproj_sk(
    const bf16* __restrict__ A,      // uc (2048, 2048)
    const bf16* __restrict__ Bw,     // x_proj_w (96, 2048)
    float* __restrict__ P)           // (4, 2048, 96) partials
{
    constexpr int N = 96;
    __shared__ __align__(16) short As[64 * 64];
    __shared__ __align__(16) short Bs[64 * 64];
    const int tid  = threadIdx.x;
    const int lane = tid & 63;
    const int wv   = tid >> 6;
    const int m0 = blockIdx.y * 64;
    const int n0 = blockIdx.x * 64;
    const int kz = blockIdx.z;           // 0..3, K range [kz*512, kz*512+512)
    const int wm = (wv >> 1) * 32;
    const int wn = (wv & 1) * 32;
    const int lr = lane & 15;
    const int lq = lane >> 4;
    const int grow = lane >> 3;
    const int gcol = (lane & 7) * 8;

    {   // zero OOB B rows (n0=64 block: rows 32..63 of Bs)
        const int z0 = (N - n0) * 64;
        uint4 z; z.x = z.y = z.z = z.w = 0;
        for (int s = z0 + tid * 8; s < 64 * 64; s += 2048)
            *(uint4*)&Bs[s] = z;
    }

    f32x4 acc[2][2] = {};
    const int kend = kz * 512 + 512;
    for (int k0 = kz * 512; k0 < kend; k0 += 64) {
        #pragma unroll
        for (int g = 0; g < 2; ++g) {
            const int gg = g * 4 + wv;
            cp16(A + (long)(m0 + gg * 8 + grow) * 2048 + k0 + gcol, &As[gg * 512]);
        }
        #pragma unroll
        for (int g = 0; g < 2; ++g) {
            const int gg = g * 4 + wv;
            if (n0 + gg * 8 < N)
                cp16(Bw + (long)(n0 + gg * 8 + grow) * 2048 + k0 + gcol, &Bs[gg * 512]);
        }
        __syncthreads();
        #pragma unroll
        for (int kk = 0; kk < 2; ++kk) {
            bf16x8 af[2], bfr[2];
            #pragma unroll
            for (int i = 0; i < 2; ++i)
                af[i] = *(const bf16x8*)&As[(wm + i * 16 + lr) * 64 + kk * 32 + lq * 8];
            #pragma unroll
            for (int j = 0; j < 2; ++j)
                bfr[j] = *(const bf16x8*)&Bs[(wn + j * 16 + lr) * 64 + kk * 32 + lq * 8];
            #pragma unroll
            for (int i = 0; i < 2; ++i)
                #pragma unroll
                for (int j = 0; j < 2; ++j)
                    acc[i][j] = __builtin_amdgcn_mfma_f32_16x16x32_bf16(
                        af[i], bfr[j], acc[i][j], 0, 0, 0);
        }
        __syncthreads();
    }

    float* Pz = P + (long)kz * (2048 * 96);
    #pragma unroll
    for (int j = 0; j < 2; ++j) {
        const int col = n0 + wn + j * 16 + lr;
        if (col >= N) continue;
        #pragma unroll
        for (int i = 0; i < 2; ++i) {
            const int r0 = m0 + wm + i * 16 + lq * 4;
            #pragma unroll
            for (int r = 0; r < 4; ++r)
                Pz[(long)(r0 + r) * 96 + col] = acc[i][j][r];
        }
    }
}

__global__ __launch_bounds__(256) void xproj_reduce(
    const float* __restrict__ P, bf16* __restrict__ dbc)
{
    const int i = blockIdx.x * 256 + threadIdx.x;   // < 196608
    const float s = P[i] + P[i + 196608] + P[i + 2 * 196608] + P[i + 3 * 196608];
    dbc[i] = __float2bfloat16(scrub(s));
}

// ---------------------------------------------------------------------------
// Depthwise causal conv (window 4) + bias + silu, vectorized: one thread
// owns 8 consecutive channels (short8 loads, 16 B/lane).  u = xz[:, 0:2048].
// ---------------------------------------------------------------------------
__global__ __launch_bounds__(256) void conv_silu_kernel(
    const bf16* __restrict__ xz, const bf16* __restrict__ cw,
    const bf16* __restrict__ cb, bf16* __restrict__ uc)
{
    const int gid = blockIdx.x * 256 + threadIdx.x;  // over 2*1024*2048/8
    const int dc  = (gid & 255) * 8;                 // channel chunk base
    const int row = gid >> 8;                        // b*1024 + t
    const int t   = row & 1023;
    // weights for channels dc..dc+7: 32 consecutive shorts (d-major, tap-minor)
    const bf16x8 w0 = *(const bf16x8*)(cw + dc * 4);
    const bf16x8 w1 = *(const bf16x8*)(cw + dc * 4 + 8);
    const bf16x8 w2 = *(const bf16x8*)(cw + dc * 4 + 16);
    const bf16x8 w3 = *(const bf16x8*)(cw + dc * 4 + 24);
    const bf16x8 bv = *(const bf16x8*)(cb + dc);
    float wf[32];
    #pragma unroll
    for (int k = 0; k < 8; ++k) {
        wf[k]      = us2f((unsigned short)w0[k]);
        wf[8 + k]  = us2f((unsigned short)w1[k]);
        wf[16 + k] = us2f((unsigned short)w2[k]);
        wf[24 + k] = us2f((unsigned short)w3[k]);
    }
    float acc[8];
    #pragma unroll
    for (int i = 0; i < 8; ++i) acc[i] = us2f((unsigned short)bv[i]);
    #pragma unroll
    for (int j = 0; j < 4; ++j) {
        const int tt = t - 3 + j;
        if (tt < 0) continue;
        const bf16x8 xv = *(const bf16x8*)(xz + (long)(row - 3 + j) * 4096 + dc);
        #pragma unroll
        for (int i = 0; i < 8; ++i)
            acc[i] += wf[i * 4 + j] * us2f((unsigned short)xv[i]);
    }
    bf16x8 o;
    #pragma unroll
    for (int i = 0; i < 8; ++i) {
        const float sg = 1.f / (1.f + __expf(-acc[i]));
        o[i] = (short)f2us(acc[i] * sg);
    }
    *(bf16x8*)(uc + (long)row * 2048 + dc) = o;
}

// ---------------------------------------------------------------------------
// Selective scan v5 -- chunked parallel scan over time.  The monolithic scan
// pinned the machine at 1 wave/SIMD (65536 chains = 1024 waves on 1024
// SIMDs) with a 101 KB LDS block (1 block/CU): Occupancy 10%, VALUBusy 27%.
// Split L=1024 into 8 chunks of 128:
//   S1 scan_carry:  2048 blocks, per-chain (A_prod, h_local from h0=0)
//   S2 scan_combine: 8-step serial combine per chain (in-place h0 write)
//   S3 scan_apply:  2048 blocks, re-run recurrence from true h0, emit y.
// Recurrence math per step is IDENTICAL to the monolithic version; only h0
// correction differs (exact in exact arithmetic, ~ulp in fp32, << bf16).
// S3's phase-3/sP (80 KB LDS) is replaced by a 4-step DPP row_shr reduce
// (pure VALU); lane n==15 of each 16-lane row stores y.
// ---------------------------------------------------------------------------
__global__ __launch_bounds__(256) void scan_carry_kernel(
    const bf16* __restrict__ delta,    // (B*L, 2048)
    const bf16* __restrict__ uc,       // (B*L, 2048)
    const bf16* __restrict__ dbc,      // (B*L, 96): dt | B | C
    const float* __restrict__ A_log,   // (2048, 16) fp32
    float2* __restrict__ carry)        // (B, 8, 2048, 16): {A_prod, h_local}
{
    const int b   = blockIdx.y;
    const int c   = blockIdx.z;
    const int d0  = blockIdx.x * 16;
    const int tid = threadIdx.x;
    const int n   = tid & 15;
    const int dl  = tid >> 4;
    const int d   = d0 + dl;

    __shared__ __align__(16) float2 sDU[64][17];
    __shared__ __align__(16) float  sB [64][17];

    const float An = -expf(A_log[d * 16 + n]);
    float h = 0.f, prod = 1.f;
    const long rowbase = (long)b * 1024 + c * 128;

    const int ltt = tid >> 2;
    const int ldg = (tid & 3) * 4;

    ushort4 rDT, rUV, rB;
    auto load_chunk = [&](int t0c) {
        const long r = rowbase + t0c + ltt;
        rDT = *(const ushort4*)((const unsigned short*)delta + r * 2048 + d0 + ldg);
        rUV = *(const ushort4*)((const unsigned short*)uc    + r * 2048 + d0 + ldg);
        rB  = *(const ushort4*)((const unsigned short*)dbc   + r * 96 + 64 + ldg);
    };
    auto store_chunk = [&]() {
        const unsigned short dt4[4] = {rDT.x, rDT.y, rDT.z, rDT.w};
        const unsigned short uv4[4] = {rUV.x, rUV.y, rUV.z, rUV.w};
        const unsigned short b4_[4] = {rB.x,  rB.y,  rB.z,  rB.w};
        #pragma unroll
        for (int j = 0; j < 4; ++j) {
            sDU[ltt][ldg + j] = float2{us2f(dt4[j]), us2f(uv4[j])};
            sB [ltt][ldg + j] = us2f(b4_[j]);
        }
    };

    load_chunk(0);
    for (int t0 = 0; t0 < 128; t0 += 64) {
        store_chunk();
        __syncthreads();
        if (t0 + 64 < 128) load_chunk(t0 + 64);

        float2 dua[8], dub[8];
        float  ba[8], bb[8];
        #pragma unroll
        for (int t = 0; t < 8; ++t) { dua[t] = sDU[t][dl]; ba[t] = sB[t][n]; }
        #pragma unroll
        for (int tb = 0; tb < 64; tb += 8) {
            if (tb < 56) {
                #pragma unroll
                for (int t = 0; t < 8; ++t) {
                    dub[t] = sDU[tb + 8 + t][dl];
                    bb[t]  = sB [tb + 8 + t][n];
                }
            }
            #pragma unroll
            for (int t = 0; t < 8; ++t) {
                const float a = __expf(dua[t].x * An);
                h = a * h + (dua[t].x * dua[t].y) * ba[t];
                prod *= a;
            }
            #pragma unroll
            for (int t = 0; t < 8; ++t) { dua[t] = dub[t]; ba[t] = bb[t]; }
        }
        __syncthreads();
    }
    carry[((long)b * 8 + c) * 32768 + d * 16 + n] = float2{prod, h};
}

__global__ __launch_bounds__(256) void scan_combine_kernel(float2* __restrict__ carry)
{
    const int gid = blockIdx.x * 256 + threadIdx.x;   // 65536 chains
    const int b   = gid >> 15;
    const int rem = gid & 32767;                      // d*16 + n
    float h = 0.f;
    #pragma unroll
    for (int c = 0; c < 8; ++c) {
        float2* p = &carry[((long)b * 8 + c) * 32768 + rem];
        const float2 AB = *p;
        ((float*)p)[0] = h;          // h0 at chunk-c start (in-place over A)
        h = AB.x * h + AB.y;
    }
}

__global__ __launch_bounds__(256) void scan_apply_kernel(
    const bf16* __restrict__ delta,    // (B*L, 2048)
    const bf16* __restrict__ uc,       // (B*L, 2048)
    const bf16* __restrict__ dbc,      // (B*L, 96): dt | B | C
    const bf16* __restrict__ xz,       // (B*L, 4096): z at cols 2048+d
    const float* __restrict__ A_log,   // (2048, 16) fp32
    const float* __restrict__ Dp,      // (2048)     fp32
    const float2* __restrict__ carry,  // h0 in .x after combine
    bf16* __restrict__ y)              // (B*L, 2048)
{
    const int b   = blockIdx.y;
    const int c   = blockIdx.z;
    const int d0  = blockIdx.x * 16;
    const int tid = threadIdx.x;
    const int n   = tid & 15;
    const int dl  = tid >> 4;
    const int d   = d0 + dl;

    __shared__ __align__(16) float2 sDU[64][17];
    __shared__ __align__(16) float2 sBC[64][17];
    __shared__ __align__(16) float  sZ [64][17];

    const float An = -expf(A_log[d * 16 + n]);
    const float Dd = Dp[d];
    float h = carry[((long)b * 8 + c) * 32768 + d * 16 + n].x;
    const long rowbase = (long)b * 1024 + c * 128;

    const int ltt = tid >> 2;
    const int ldg = (tid & 3) * 4;

    ushort4 rDT, rUV, rB, rC, rZ;
    auto load_chunk = [&](int t0c) {
        const long r = rowbase + t0c + ltt;
        rDT = *(const ushort4*)((const unsigned short*)delta + r * 2048 + d0 + ldg);
        rUV = *(const ushort4*)((const unsigned short*)uc    + r * 2048 + d0 + ldg);
        rB  = *(const ushort4*)((const unsigned short*)dbc   + r * 96 + 64 + ldg);
        rC  = *(const ushort4*)((const unsigned short*)dbc   + r * 96 + 80 + ldg);
        rZ  = *(const ushort4*)((const unsigned short*)xz    + r * 4096 + 2048 + d0 + ldg);
    };
    auto store_chunk = [&]() {
        const unsigned short dt4[4] = {rDT.x, rDT.y, rDT.z, rDT.w};
        const unsigned short uv4[4] = {rUV.x, rUV.y, rUV.z, rUV.w};
        const unsigned short b4_[4] = {rB.x,  rB.y,  rB.z,  rB.w};
        const unsigned short c4_[4] = {rC.x,  rC.y,  rC.z,  rC.w};
        const unsigned short z4_[4] = {rZ.x,  rZ.y,  rZ.z,  rZ.w};
        #pragma unroll
        for (int j = 0; j < 4; ++j) {
            sDU[ltt][ldg + j] = float2{us2f(dt4[j]), us2f(uv4[j])};
            sBC[ltt][ldg + j] = float2{us2f(b4_[j]), us2f(c4_[j])};
            const float zz = us2f(z4_[j]);
            sZ[ltt][ldg + j] = zz / (1.f + __expf(-zz));
        }
    };

    load_chunk(0);
    for (int t0 = 0; t0 < 128; t0 += 64) {
        store_chunk();
        __syncthreads();
        if (t0 + 64 < 128) load_chunk(t0 + 64);

        float2 dua[8], bca[8], dub[8], bcb[8];
        #pragma unroll
        for (int t = 0; t < 8; ++t) { dua[t] = sDU[t][dl]; bca[t] = sBC[t][n]; }
        #pragma unroll
        for (int tb = 0; tb < 64; tb += 8) {
            if (tb < 56) {
                #pragma unroll
                for (int t = 0; t < 8; ++t) {
                    dub[t] = sDU[tb + 8 + t][dl];
                    bcb[t] = sBC[tb + 8 + t][n];
                }
            }
            #pragma unroll
            for (int t = 0; t < 8; ++t) {
                const float a = __expf(dua[t].x * An);
                h = a * h + (dua[t].x * dua[t].y) * bca[t].x;
                float p = h * bca[t].y;
                if (n == 0) p += dua[t].y * Dd;
                // 16-lane row reduce (DPP, pure VALU); lane n==15 gets sum
                p = dpp_shr_add<0x111>(p);
                p = dpp_shr_add<0x112>(p);
                p = dpp_shr_add<0x114>(p);
                p = dpp_shr_add<0x118>(p);
                if (n == 15) {
                    const float yv = p * sZ[tb + t][dl];
                    y[(rowbase + t0 + tb + t) * 2048 + d] = __float2bfloat16(yv);
                }
            }
            #pragma unroll
            for (int t = 0; t < 8; ++t) { dua[t] = dub[t]; bca[t] = bcb[t]; }
        }
        __syncthreads();
    }
}

// ---------------------------------------------------------------------------
extern "C" void kernel_launch(void* const* d_in, const int* in_sizes, int n_in,
                              void* d_out, int out_size, void* d_ws, size_t ws_size,
                              hipStream_t stream)
{
    char* ws = (char*)d_ws;
    const size_t MiB = 1048576;

    bf16*  xn  = (bf16*)(ws);                    // [ 0, 4): (2048,1024) ln1 out
    bf16*  xz  = (bf16*)(ws +  4 * MiB);         // [ 4,20): (2048,4096) in_proj out
    bf16*  uc  = (bf16*)(ws + 20 * MiB);         // [20,28): (2048,2048) conv+silu out
    bf16*  dbc = (bf16*)(ws + 28 * MiB);         // [28,28.4): (2048,96)
    bf16*  dlb = (bf16*)(ws + 28 * MiB + 524288);// [28.5,36.5): delta; scan writes y in-place
    bf16*  yb  = dlb;                            //   (element-aliased, safe per-row)
    float* hb  = (float*)(ws);                   // [ 0, 8): f32 resid (xn/xz dead at step 7)
    float* xpp = (float*)(ws);                   // [ 0, 3): x_proj split-K partials (xn dead)
    float2* carry = (float2*)(ws);               // [ 0, 4): scan carries (xpp dead by then)
    bf16*  hn  = (bf16*)(ws +  8 * MiB);         // [ 8,12): ln2 out (over dead xz)
    bf16*  gb  = (bf16*)(ws + 12 * MiB);         // [12,20): mlp1 out (over dead xz)
    unsigned short* cvt = (unsigned short*)(ws + 37 * MiB);  // [37, 61.8): bf16 inputs

    const float* xf     = (const float*)d_in[0];
    const float* A_logf = (const float*)d_in[9];
    const float* Dpf    = (const float*)d_in[10];

    const bf16* in_proj_w  = (const bf16*)(cvt + 2099200);
    const bf16* conv_w     = (const bf16*)(cvt + 6293504);
    const bf16* conv_b     = (const bf16*)(cvt + 6301696);
    const bf16* x_proj_w   = (const bf16*)(cvt + 6303744);
    const bf16* dt_proj_w  = (const bf16*)(cvt + 6500352);
    const bf16* dt_proj_b  = (const bf16*)(cvt + 6631424);
    const bf16* out_proj_w = (const bf16*)(cvt + 6668288);
    const bf16* ln2_w      = (const bf16*)(cvt + 8765440);
    const bf16* ln2_b      = (const bf16*)(cvt + 8766464);
    const bf16* mlp_w1     = (const bf16*)(cvt + 8767488);
    const bf16* mlp_b1     = (const bf16*)(cvt + 10864640);
    const bf16* mlp_w2     = (const bf16*)(cvt + 10866688);
    const bf16* mlp_b2     = (const bf16*)(cvt + 12963840);

    // 0+1. fused: weight conversion fp32->bf16 (x skipped) + LN1
    Ptrs ptrs;
    for (int i = 0; i < 18; ++i) ptrs.p[i] = d_in[i];
    convert_ln1_kernel<<<7355, 256, 0, stream>>>(ptrs, cvt, xn);

    // 2. in_proj: (2048,4096,K=1024)  128x128, 512 blocks (2/CU)
    gemm_as<128, 128, 0, false, bf16, bf16><<<dim3(32, 16), 256, 0, stream>>>(
        xn, 1024, in_proj_w, 1024, xz, 4096, nullptr, (const bf16*)nullptr, 2048, 4096, 1024);
    // 3. depthwise causal conv + bias + silu -> uc (short8-vectorized)
    conv_silu_kernel<<<2048, 256, 0, stream>>>(xz, conv_w, conv_b, uc);
    // 4. x_proj split-K=4: (2048,96,K=2048) -> fp32 partials -> bf16 dbc
    gemm_xproj_sk<<<dim3(2, 32, 4), 256, 0, stream>>>(uc, x_proj_w, xpp);
    xproj_reduce<<<768, 256, 0, stream>>>(xpp, dbc);
    // 5. dt_proj + softplus: (2048,2048,K=64)  64x64, 1024 blocks (4/CU)
    gemm_as<64, 64, 2, false, bf16, bf16><<<dim3(32, 32), 256, 0, stream>>>(
        dbc, 96, dt_proj_w, 64, dlb, 2048, dt_proj_b, (const bf16*)nullptr, 2048, 2048, 64);
    // 6. selective scan, chunked-parallel (8 time-chunks of 128)
    scan_carry_kernel<<<dim3(128, 2, 8), 256, 0, stream>>>(dlb, uc, dbc, A_logf, carry);
    scan_combine_kernel<<<256, 256, 0, stream>>>(carry);
    scan_apply_kernel<<<dim3(128, 2, 8), 256, 0, stream>>>(
        dlb, uc, dbc, xz, A_logf, Dpf, carry, yb);
    // 7. out_proj + residual x (fp32): (2048,1024,K=2048)  64x64, 512 blocks
    gemm_as<64, 64, 0, false, float, float><<<dim3(16, 32), 256, 0, stream>>>(
        yb, 2048, out_proj_w, 2048, hb, 1024, nullptr, xf, 2048, 1024, 2048);
    // 8. LN2
    ln_kernel<float><<<2048, 256, 0, stream>>>(hb, ln2_w, ln2_b, hn);
    // 9. MLP1 + gelu: (2048,2048,K=1024)  128x64 tile, 512 blocks (2/CU)
    gemm_as<128, 64, 1, false, bf16, bf16><<<dim3(32, 16), 256, 0, stream>>>(
        hn, 1024, mlp_w1, 1024, gb, 2048, mlp_b1, (const bf16*)nullptr, 2048, 2048, 1024);
    // 10. MLP2 + bias + residual h -> d_out (fp32): 64x64, 512 blocks
    gemm_as<64, 64, 0, false, float, float><<<dim3(16, 32), 256, 0, stream>>>(
        gb, 2048, mlp_w2, 2048, (float*)d_out, 1024, mlp_b2, hb, 2048, 1024, 2048);
}

// Round 9
// 327.347 us; speedup vs baseline: 1.1339x; 1.1339x over previous
//
#include <hip/hip_runtime.h>
#include <hip/hip_bf16.h>
#include <math.h>

typedef __hip_bfloat16 bf16;
typedef __attribute__((ext_vector_type(8))) short bf16x8;
typedef __attribute__((ext_vector_type(4))) float f32x4;

__device__ __forceinline__ float b2f(bf16 x) { return __bfloat162float(x); }
__device__ __forceinline__ float us2f(unsigned short u) {
    return __uint_as_float(((unsigned int)u) << 16);
}
__device__ __forceinline__ unsigned short f2us(float f) {
    bf16 t = __float2bfloat16(f);
    return *reinterpret_cast<unsigned short*>(&t);
}
__device__ __forceinline__ float scrub(float v) {
    return (v == v && fabsf(v) < 3.0e38f) ? v : 0.f;
}
__device__ __forceinline__ float to_float(float x) { return x; }
__device__ __forceinline__ float to_float(bf16 x) { return __bfloat162float(x); }
__device__ __forceinline__ void store_out(float* p, float v) { *p = v; }
__device__ __forceinline__ void store_out(bf16* p, float v) { *p = __float2bfloat16(v); }

// async global->LDS, 16 B per lane; LDS dest = wave-uniform base + lane*16
__device__ __forceinline__ void cp16(const void* g, void* l) {
    __builtin_amdgcn_global_load_lds(
        (const __attribute__((address_space(1))) unsigned int*)g,
        (__attribute__((address_space(3))) unsigned int*)l, 16, 0, 0);
}

// ---------------------------------------------------------------------------
// Fused: weight conversion fp32->bf16 (x skipped) + LayerNorm-1 over x.
// ---------------------------------------------------------------------------
struct Ptrs { const void* p[18]; };

__constant__ __device__ const long TOFF[19] = {
    0,         2097152,  2098176,  2099200,  6293504,  6301696,  6303744,
    6500352,   6631424,  6633472,  6666240,  6668288,  8765440,  8766464,
    8767488,   10864640, 10866688, 12963840, 12964864};

__global__ __launch_bounds__(256) void convert_ln1_kernel(
    Ptrs ptrs, unsigned short* __restrict__ dst, bf16* __restrict__ out)
{
    __shared__ float red[8];
    if (blockIdx.x < 5307) {
        const long g = 262144 + (long)blockIdx.x * 256 + threadIdx.x;
        if (g >= 1620608) return;            // 12,964,864 / 8
        const long e0 = g * 8;
        int t = 1;                           // e0 >= TOFF[1] always here
        #pragma unroll
        for (int i = 2; i < 18; ++i) t += (e0 >= TOFF[i]) ? 1 : 0;
        const long local = e0 - TOFF[t];
        const float4* ps = (const float4*)((const float*)ptrs.p[t] + local);
        const float4 a = ps[0], b = ps[1];
        ushort4 o0, o1;
        o0.x = f2us(a.x); o0.y = f2us(a.y); o0.z = f2us(a.z); o0.w = f2us(a.w);
        o1.x = f2us(b.x); o1.y = f2us(b.y); o1.z = f2us(b.z); o1.w = f2us(b.w);
        *(ushort4*)(dst + e0)     = o0;
        *(ushort4*)(dst + e0 + 4) = o1;
        return;
    }
    // ---- LN1: one block per row, 256 threads x 4 elems, fp32 weights ----
    const int row = blockIdx.x - 5307;
    const int tid = threadIdx.x;
    const float* xf = (const float*)ptrs.p[0];
    const float4 raw = ((const float4*)(xf + (long)row * 1024))[tid];
    float v[4] = {raw.x, raw.y, raw.z, raw.w};
    float s  = v[0] + v[1] + v[2] + v[3];
    float s2 = v[0]*v[0] + v[1]*v[1] + v[2]*v[2] + v[3]*v[3];
    #pragma unroll
    for (int o = 32; o > 0; o >>= 1) {
        s  += __shfl_xor(s, o);
        s2 += __shfl_xor(s2, o);
    }
    if ((tid & 63) == 0) { red[tid >> 6] = s; red[4 + (tid >> 6)] = s2; }
    __syncthreads();
    s  = red[0] + red[1] + red[2] + red[3];
    s2 = red[4] + red[5] + red[6] + red[7];
    const float mu  = s * (1.f / 1024.f);
    const float var = fmaxf(s2 * (1.f / 1024.f) - mu * mu, 0.f);
    const float rs  = rsqrtf(var + 1e-5f);
    const float4 w4 = ((const float4*)ptrs.p[1])[tid];
    const float4 b4 = ((const float4*)ptrs.p[2])[tid];
    ushort4 o;
    o.x = f2us((v[0] - mu) * rs * w4.x + b4.x);
    o.y = f2us((v[1] - mu) * rs * w4.y + b4.y);
    o.z = f2us((v[2] - mu) * rs * w4.z + b4.z);
    o.w = f2us((v[3] - mu) * rs * w4.w + b4.w);
    ((ushort4*)((unsigned short*)out + (long)row * 1024))[tid] = o;
}

// ---------------------------------------------------------------------------
// LayerNorm (generic, bf16 weights): used for LN2 over fp32 residual.
// ---------------------------------------------------------------------------
template <typename TIN>
__global__ __launch_bounds__(256) void ln_kernel(
    const TIN* __restrict__ in, const bf16* __restrict__ gw,
    const bf16* __restrict__ gb, bf16* __restrict__ out)
{
    const int row = blockIdx.x;
    const int tid = threadIdx.x;
    float v[4];
    if constexpr (sizeof(TIN) == 2) {
        ushort4 raw = ((const ushort4*)((const unsigned short*)in + (long)row * 1024))[tid];
        v[0] = us2f(raw.x); v[1] = us2f(raw.y); v[2] = us2f(raw.z); v[3] = us2f(raw.w);
    } else {
        float4 raw = ((const float4*)((const float*)in + (long)row * 1024))[tid];
        v[0] = raw.x; v[1] = raw.y; v[2] = raw.z; v[3] = raw.w;
    }
    float s  = v[0] + v[1] + v[2] + v[3];
    float s2 = v[0]*v[0] + v[1]*v[1] + v[2]*v[2] + v[3]*v[3];
    #pragma unroll
    for (int o = 32; o > 0; o >>= 1) {
        s  += __shfl_xor(s, o);
        s2 += __shfl_xor(s2, o);
    }
    __shared__ float red[8];
    if ((tid & 63) == 0) { red[tid >> 6] = s; red[4 + (tid >> 6)] = s2; }
    __syncthreads();
    s  = red[0] + red[1] + red[2] + red[3];
    s2 = red[4] + red[5] + red[6] + red[7];
    const float mu  = s * (1.f / 1024.f);
    const float var = fmaxf(s2 * (1.f / 1024.f) - mu * mu, 0.f);
    const float rs  = rsqrtf(var + 1e-5f);
    const int c0 = tid * 4;
    ushort4 o;
    o.x = f2us((v[0] - mu) * rs * b2f(gw[c0 + 0]) + b2f(gb[c0 + 0]));
    o.y = f2us((v[1] - mu) * rs * b2f(gw[c0 + 1]) + b2f(gb[c0 + 1]));
    o.z = f2us((v[2] - mu) * rs * b2f(gw[c0 + 2]) + b2f(gb[c0 + 2]));
    o.w = f2us((v[3] - mu) * rs * b2f(gw[c0 + 3]) + b2f(gb[c0 + 3]));
    ((ushort4*)((unsigned short*)out + (long)row * 1024))[tid] = o;
}

// ---------------------------------------------------------------------------
// GEMM v2 (m97-style): C[M,N] = act(A[M,K] @ Bw[N,K]^T + bias) + res.
// ---------------------------------------------------------------------------
template <int BM, int BN, int ACT, bool NG, typename TOUT, typename TRES>
__global__ __launch_bounds__(256) void gemm_as(
    const bf16* __restrict__ A, int lda,
    const bf16* __restrict__ Bw, int ldb,
    TOUT* __restrict__ C, int ldc,
    const bf16* __restrict__ bias,
    const TRES* __restrict__ res,
    int M, int N, int K)
{
    constexpr int AI = BM / 32;
    constexpr int BJ = BN / 32;
    __shared__ __align__(16) short As[BM * 64];
    __shared__ __align__(16) short Bs[BN * 64];
    const int tid  = threadIdx.x;
    const int lane = tid & 63;
    const int wv   = tid >> 6;
    const int m0 = blockIdx.y * BM;
    const int n0 = blockIdx.x * BN;
    const int wm = (wv >> 1) * (BM / 2);
    const int wn = (wv & 1) * (BN / 2);
    const int lr = lane & 15;
    const int lq = lane >> 4;
    const int grow = lane >> 3;         // row 0..7 within an 8-row group
    const int gcol = (lane & 7) * 8;    // 16B chunk (shorts)

    if (NG) {
        const int z0 = (N - n0) * 64;
        uint4 z; z.x = z.y = z.z = z.w = 0;
        for (int s = z0 + tid * 8; s < BN * 64; s += 2048)
            *(uint4*)&Bs[s] = z;
    }

    f32x4 acc[AI][BJ] = {};

    for (int k0 = 0; k0 < K; k0 += 64) {
        #pragma unroll
        for (int g = 0; g < BM / 32; ++g) {
            const int gg = g * 4 + wv;   // wave-uniform 8-row group
            cp16(A + (long)(m0 + gg * 8 + grow) * lda + k0 + gcol, &As[gg * 512]);
        }
        #pragma unroll
        for (int g = 0; g < BN / 32; ++g) {
            const int gg = g * 4 + wv;
            if (!NG || n0 + gg * 8 < N)
                cp16(Bw + (long)(n0 + gg * 8 + grow) * ldb + k0 + gcol, &Bs[gg * 512]);
        }
        __syncthreads();

        #pragma unroll
        for (int kk = 0; kk < 2; ++kk) {
            bf16x8 af[AI], bfr[BJ];
            #pragma unroll
            for (int i = 0; i < AI; ++i)
                af[i] = *(const bf16x8*)&As[(wm + i * 16 + lr) * 64 + kk * 32 + lq * 8];
            #pragma unroll
            for (int j = 0; j < BJ; ++j)
                bfr[j] = *(const bf16x8*)&Bs[(wn + j * 16 + lr) * 64 + kk * 32 + lq * 8];
            #pragma unroll
            for (int i = 0; i < AI; ++i)
                #pragma unroll
                for (int j = 0; j < BJ; ++j)
                    acc[i][j] = __builtin_amdgcn_mfma_f32_16x16x32_bf16(
                        af[i], bfr[j], acc[i][j], 0, 0, 0);
        }
        __syncthreads();
    }

    #pragma unroll
    for (int j = 0; j < BJ; ++j) {
        const int col = n0 + wn + j * 16 + lr;
        if (col >= N) continue;
        const float bv = bias ? b2f(bias[col]) : 0.f;
        #pragma unroll
        for (int i = 0; i < AI; ++i) {
            const int r0 = m0 + wm + i * 16 + lq * 4;
            #pragma unroll
            for (int r = 0; r < 4; ++r) {
                const long row = r0 + r;
                float v = acc[i][j][r] + bv;
                if (ACT == 1) v = 0.5f * v * (1.f + erff(v * 0.70710678118f));
                if (ACT == 2) v = (v > 20.f) ? v : __logf(1.f + __expf(v));
                if (res) v += to_float(res[row * (long)ldc + col]);
                store_out(&C[row * (long)ldc + col], scrub(v));
            }
        }
    }
}

// ---------------------------------------------------------------------------
// x_proj split-K: (M=2048, N=96, K=2048), 4 K-ranges, fp32 partials + reduce.
// ---------------------------------------------------------------------------
__global__ __launch_bounds__(256) void gemm_xproj_sk(
    const bf16* __restrict__ A,      // uc (2048, 2048)
    const bf16* __restrict__ Bw,     // x_proj_w (96, 2048)
    float* __restrict__ P)           // (4, 2048, 96) partials
{
    constexpr int N = 96;
    __shared__ __align__(16) short As[64 * 64];
    __shared__ __align__(16) short Bs[64 * 64];
    const int tid  = threadIdx.x;
    const int lane = tid & 63;
    const int wv   = tid >> 6;
    const int m0 = blockIdx.y * 64;
    const int n0 = blockIdx.x * 64;
    const int kz = blockIdx.z;           // 0..3
    const int wm = (wv >> 1) * 32;
    const int wn = (wv & 1) * 32;
    const int lr = lane & 15;
    const int lq = lane >> 4;
    const int grow = lane >> 3;
    const int gcol = (lane & 7) * 8;

    {   // zero OOB B rows
        const int z0 = (N - n0) * 64;
        uint4 z; z.x = z.y = z.z = z.w = 0;
        for (int s = z0 + tid * 8; s < 64 * 64; s += 2048)
            *(uint4*)&Bs[s] = z;
    }

    f32x4 acc[2][2] = {};
    const int kend = kz * 512 + 512;
    for (int k0 = kz * 512; k0 < kend; k0 += 64) {
        #pragma unroll
        for (int g = 0; g < 2; ++g) {
            const int gg = g * 4 + wv;
            cp16(A + (long)(m0 + gg * 8 + grow) * 2048 + k0 + gcol, &As[gg * 512]);
        }
        #pragma unroll
        for (int g = 0; g < 2; ++g) {
            const int gg = g * 4 + wv;
            if (n0 + gg * 8 < N)
                cp16(Bw + (long)(n0 + gg * 8 + grow) * 2048 + k0 + gcol, &Bs[gg * 512]);
        }
        __syncthreads();
        #pragma unroll
        for (int kk = 0; kk < 2; ++kk) {
            bf16x8 af[2], bfr[2];
            #pragma unroll
            for (int i = 0; i < 2; ++i)
                af[i] = *(const bf16x8*)&As[(wm + i * 16 + lr) * 64 + kk * 32 + lq * 8];
            #pragma unroll
            for (int j = 0; j < 2; ++j)
                bfr[j] = *(const bf16x8*)&Bs[(wn + j * 16 + lr) * 64 + kk * 32 + lq * 8];
            #pragma unroll
            for (int i = 0; i < 2; ++i)
                #pragma unroll
                for (int j = 0; j < 2; ++j)
                    acc[i][j] = __builtin_amdgcn_mfma_f32_16x16x32_bf16(
                        af[i], bfr[j], acc[i][j], 0, 0, 0);
        }
        __syncthreads();
    }

    float* Pz = P + (long)kz * (2048 * 96);
    #pragma unroll
    for (int j = 0; j < 2; ++j) {
        const int col = n0 + wn + j * 16 + lr;
        if (col >= N) continue;
        #pragma unroll
        for (int i = 0; i < 2; ++i) {
            const int r0 = m0 + wm + i * 16 + lq * 4;
            #pragma unroll
            for (int r = 0; r < 4; ++r)
                Pz[(long)(r0 + r) * 96 + col] = acc[i][j][r];
        }
    }
}

__global__ __launch_bounds__(256) void xproj_reduce(
    const float* __restrict__ P, bf16* __restrict__ dbc)
{
    const int i = blockIdx.x * 256 + threadIdx.x;   // < 196608
    const float s = P[i] + P[i + 196608] + P[i + 2 * 196608] + P[i + 3 * 196608];
    dbc[i] = __float2bfloat16(scrub(s));
}

// ---------------------------------------------------------------------------
// Depthwise causal conv (window 4) + bias + silu, short8-vectorized.
// ---------------------------------------------------------------------------
__global__ __launch_bounds__(256) void conv_silu_kernel(
    const bf16* __restrict__ xz, const bf16* __restrict__ cw,
    const bf16* __restrict__ cb, bf16* __restrict__ uc)
{
    const int gid = blockIdx.x * 256 + threadIdx.x;
    const int dc  = (gid & 255) * 8;
    const int row = gid >> 8;
    const int t   = row & 1023;
    const bf16x8 w0 = *(const bf16x8*)(cw + dc * 4);
    const bf16x8 w1 = *(const bf16x8*)(cw + dc * 4 + 8);
    const bf16x8 w2 = *(const bf16x8*)(cw + dc * 4 + 16);
    const bf16x8 w3 = *(const bf16x8*)(cw + dc * 4 + 24);
    const bf16x8 bv = *(const bf16x8*)(cb + dc);
    float wf[32];
    #pragma unroll
    for (int k = 0; k < 8; ++k) {
        wf[k]      = us2f((unsigned short)w0[k]);
        wf[8 + k]  = us2f((unsigned short)w1[k]);
        wf[16 + k] = us2f((unsigned short)w2[k]);
        wf[24 + k] = us2f((unsigned short)w3[k]);
    }
    float acc[8];
    #pragma unroll
    for (int i = 0; i < 8; ++i) acc[i] = us2f((unsigned short)bv[i]);
    #pragma unroll
    for (int j = 0; j < 4; ++j) {
        const int tt = t - 3 + j;
        if (tt < 0) continue;
        const bf16x8 xv = *(const bf16x8*)(xz + (long)(row - 3 + j) * 4096 + dc);
        #pragma unroll
        for (int i = 0; i < 8; ++i)
            acc[i] += wf[i * 4 + j] * us2f((unsigned short)xv[i]);
    }
    bf16x8 o;
    #pragma unroll
    for (int i = 0; i < 8; ++i) {
        const float sg = 1.f / (1.f + __expf(-acc[i]));
        o[i] = (short)f2us(acc[i] * sg);
    }
    *(bf16x8*)(uc + (long)row * 2048 + dc) = o;
}

// ---------------------------------------------------------------------------
// Selective scan v6 -- n-VECTORIZED chunked scan.  R7 measurement proved the
// scan is THROUGHPUT-bound on per-step work (2048x128 chunked == 256x1024
// monolithic == 75us).  Cut per-chain-step instructions: each lane owns ONE
// channel d and all 16 n chains in registers (An[16], h[16]).  Per wave-step
// ~100 instrs serve 64 d x 16 n = 1024 chain-steps (3.4x less issue than the
// (d,n)-per-lane layout), y is lane-local (no DPP chain, no divergent store,
// coalesced 128B/wave stores), dt*u computed once (not 16x redundantly).
// NC=16 chunks of 64 steps; blocks = 128 threads (128 d); grid (16,2,16).
// Carry buffer = float2[2*16*32768] = exactly 8 MiB -> lives in d_out
// (free scratch until step 10 fully overwrites it).
// ---------------------------------------------------------------------------
__global__ __launch_bounds__(128) void scan_carry_kernel(
    const bf16* __restrict__ delta,    // (B*L, 2048)
    const bf16* __restrict__ uc,       // (B*L, 2048)
    const bf16* __restrict__ dbc,      // (B*L, 96): dt | B | C
    const float* __restrict__ A_log,   // (2048, 16) fp32
    float2* __restrict__ carry)        // (B, 16, 2048, 16): {A_prod, h_local}
{
    const int d0  = blockIdx.x * 128;
    const int b   = blockIdx.y;
    const int c   = blockIdx.z;        // 0..15
    const int tid = threadIdx.x;       // 0..127
    const int lane = tid & 63;
    const int wv   = tid >> 6;         // 0..1
    const int d    = d0 + tid;

    __shared__ __align__(16) unsigned short sDT[64][128];  // 16 KB
    __shared__ __align__(16) unsigned short sU [64][128];  // 16 KB
    __shared__ __align__(16) float sB[64][16];             //  4 KB

    float An[16];
    {
        const float4* ap = (const float4*)(A_log + (long)d * 16);
        #pragma unroll
        for (int q = 0; q < 4; ++q) {
            const float4 a4 = ap[q];
            An[q*4+0] = -expf(a4.x); An[q*4+1] = -expf(a4.y);
            An[q*4+2] = -expf(a4.z); An[q*4+3] = -expf(a4.w);
        }
    }

    const long r0 = (long)b * 1024 + c * 64;

    // stage dt,u: per cp16 a wave moves 4 rows (16 lanes x 16B per row)
    const int srow = lane >> 4;
    const int scol = (lane & 15) * 8;
    #pragma unroll
    for (int g = 0; g < 8; ++g) {
        const int grp = g * 2 + wv;           // 0..15, 4 rows each
        const long r = r0 + grp * 4 + srow;
        cp16((const unsigned short*)delta + r * 2048 + d0 + scol, &sDT[grp * 4][0]);
        cp16((const unsigned short*)uc    + r * 2048 + d0 + scol, &sU [grp * 4][0]);
    }
    // stage B (64 rows x 16 bf16) -> f32
    #pragma unroll
    for (int k = 0; k < 2; ++k) {
        const int q = tid + k * 128;          // 0..255
        const int row = q >> 2, quad = q & 3;
        const ushort4 v = *(const ushort4*)((const unsigned short*)dbc
                              + (r0 + row) * 96 + 64 + quad * 4);
        sB[row][quad*4+0] = us2f(v.x); sB[row][quad*4+1] = us2f(v.y);
        sB[row][quad*4+2] = us2f(v.z); sB[row][quad*4+3] = us2f(v.w);
    }

    float h[16], pr[16];
    #pragma unroll
    for (int n = 0; n < 16; ++n) { h[n] = 0.f; pr[n] = 1.f; }
    __syncthreads();   // drains vmcnt (cp16) before LDS reads

    #pragma unroll 2
    for (int t = 0; t < 64; ++t) {
        const float dt = us2f(sDT[t][tid]);
        const float u  = us2f(sU [t][tid]);
        const float s  = dt * u;
        const float4 b0 = *(const float4*)&sB[t][0];
        const float4 b1 = *(const float4*)&sB[t][4];
        const float4 b2 = *(const float4*)&sB[t][8];
        const float4 b3 = *(const float4*)&sB[t][12];
        const float Bv[16] = {b0.x,b0.y,b0.z,b0.w, b1.x,b1.y,b1.z,b1.w,
                              b2.x,b2.y,b2.z,b2.w, b3.x,b3.y,b3.z,b3.w};
        #pragma unroll
        for (int n = 0; n < 16; ++n) {
            const float a = __expf(dt * An[n]);
            h[n]  = a * h[n] + s * Bv[n];
            pr[n] *= a;
        }
    }
    float2* cp = carry + ((long)(b * 16 + c) * 32768 + (long)d * 16);
    #pragma unroll
    for (int n = 0; n < 16; ++n) cp[n] = float2{pr[n], h[n]};
}

__global__ __launch_bounds__(256) void scan_combine_kernel(float2* __restrict__ carry)
{
    const int gid = blockIdx.x * 256 + threadIdx.x;   // 65536 chains
    const int b   = gid >> 15;
    const int rem = gid & 32767;                      // d*16 + n
    float h = 0.f;
    #pragma unroll
    for (int c = 0; c < 16; ++c) {
        float2* p = &carry[((long)b * 16 + c) * 32768 + rem];
        const float2 AB = *p;
        ((float*)p)[0] = h;          // h0 entering chunk c (in-place over A)
        h = AB.x * h + AB.y;
    }
}

__global__ __launch_bounds__(128) void scan_apply_kernel(
    const bf16* __restrict__ delta,    // (B*L, 2048)
    const bf16* __restrict__ uc,       // (B*L, 2048)
    const bf16* __restrict__ dbc,      // (B*L, 96): dt | B | C
    const bf16* __restrict__ xz,       // (B*L, 4096): z at cols 2048+d
    const float* __restrict__ A_log,   // (2048, 16) fp32
    const float* __restrict__ Dp,      // (2048)     fp32
    const float2* __restrict__ carry,  // h0 in .x after combine
    bf16* __restrict__ y)              // (B*L, 2048)
{
    const int d0  = blockIdx.x * 128;
    const int b   = blockIdx.y;
    const int c   = blockIdx.z;
    const int tid = threadIdx.x;
    const int lane = tid & 63;
    const int wv   = tid >> 6;
    const int d    = d0 + tid;

    __shared__ __align__(16) unsigned short sDT[64][128];  // 16 KB
    __shared__ __align__(16) unsigned short sU [64][128];  // 16 KB
    __shared__ __align__(16) unsigned short sZ [64][128];  // 16 KB
    __shared__ __align__(16) float sB[64][16];             //  4 KB
    __shared__ __align__(16) float sC[64][16];             //  4 KB

    float An[16];
    {
        const float4* ap = (const float4*)(A_log + (long)d * 16);
        #pragma unroll
        for (int q = 0; q < 4; ++q) {
            const float4 a4 = ap[q];
            An[q*4+0] = -expf(a4.x); An[q*4+1] = -expf(a4.y);
            An[q*4+2] = -expf(a4.z); An[q*4+3] = -expf(a4.w);
        }
    }
    const float Dd = Dp[d];

    const long r0 = (long)b * 1024 + c * 64;

    const int srow = lane >> 4;
    const int scol = (lane & 15) * 8;
    #pragma unroll
    for (int g = 0; g < 8; ++g) {
        const int grp = g * 2 + wv;
        const long r = r0 + grp * 4 + srow;
        cp16((const unsigned short*)delta + r * 2048 + d0 + scol, &sDT[grp * 4][0]);
        cp16((const unsigned short*)uc    + r * 2048 + d0 + scol, &sU [grp * 4][0]);
        cp16((const unsigned short*)xz    + r * 4096 + 2048 + d0 + scol, &sZ[grp * 4][0]);
    }
    // stage B,C (64 rows x 32 bf16) -> f32
    #pragma unroll
    for (int k = 0; k < 4; ++k) {
        const int q = tid + k * 128;          // 0..511
        const int row = q >> 3, quad = q & 7;
        const ushort4 v = *(const ushort4*)((const unsigned short*)dbc
                              + (r0 + row) * 96 + 64 + quad * 4);
        float* dst = (quad < 4) ? &sB[row][quad * 4] : &sC[row][(quad - 4) * 4];
        dst[0] = us2f(v.x); dst[1] = us2f(v.y); dst[2] = us2f(v.z); dst[3] = us2f(v.w);
    }

    // h0: 16 consecutive float2 = 8 float4 per lane, contiguous 128B
    float h[16];
    {
        const float4* hp = (const float4*)(carry + ((long)(b * 16 + c) * 32768
                                                    + (long)d * 16));
        #pragma unroll
        for (int k = 0; k < 8; ++k) {
            const float4 v = hp[k];
            h[2*k]   = v.x;    // .x of float2 pair 2k
            h[2*k+1] = v.z;    // .x of float2 pair 2k+1
        }
    }
    __syncthreads();

    unsigned short* yp = (unsigned short*)y + r0 * 2048 + d;

    #pragma unroll 2
    for (int t = 0; t < 64; ++t) {
        const float dt = us2f(sDT[t][tid]);
        const float u  = us2f(sU [t][tid]);
        const float zz = us2f(sZ [t][tid]);
        const float s  = dt * u;
        const float4 b0 = *(const float4*)&sB[t][0];
        const float4 b1 = *(const float4*)&sB[t][4];
        const float4 b2 = *(const float4*)&sB[t][8];
        const float4 b3 = *(const float4*)&sB[t][12];
        const float4 c0 = *(const float4*)&sC[t][0];
        const float4 c1 = *(const float4*)&sC[t][4];
        const float4 c2 = *(const float4*)&sC[t][8];
        const float4 c3 = *(const float4*)&sC[t][12];
        const float Bv[16] = {b0.x,b0.y,b0.z,b0.w, b1.x,b1.y,b1.z,b1.w,
                              b2.x,b2.y,b2.z,b2.w, b3.x,b3.y,b3.z,b3.w};
        const float Cv[16] = {c0.x,c0.y,c0.z,c0.w, c1.x,c1.y,c1.z,c1.w,
                              c2.x,c2.y,c2.z,c2.w, c3.x,c3.y,c3.z,c3.w};
        float y0 = 0.f, y1 = 0.f, y2 = 0.f, y3 = 0.f;
        #pragma unroll
        for (int n = 0; n < 4; ++n) {
            const float a = __expf(dt * An[n]);
            h[n] = a * h[n] + s * Bv[n];
            y0 += h[n] * Cv[n];
        }
        #pragma unroll
        for (int n = 4; n < 8; ++n) {
            const float a = __expf(dt * An[n]);
            h[n] = a * h[n] + s * Bv[n];
            y1 += h[n] * Cv[n];
        }
        #pragma unroll
        for (int n = 8; n < 12; ++n) {
            const float a = __expf(dt * An[n]);
            h[n] = a * h[n] + s * Bv[n];
            y2 += h[n] * Cv[n];
        }
        #pragma unroll
        for (int n = 12; n < 16; ++n) {
            const float a = __expf(dt * An[n]);
            h[n] = a * h[n] + s * Bv[n];
            y3 += h[n] * Cv[n];
        }
        const float ys  = (y0 + y1) + (y2 + y3) + u * Dd;
        const float sil = zz / (1.f + __expf(-zz));
        yp[(long)t * 2048] = f2us(ys * sil);
    }
}

// ---------------------------------------------------------------------------
extern "C" void kernel_launch(void* const* d_in, const int* in_sizes, int n_in,
                              void* d_out, int out_size, void* d_ws, size_t ws_size,
                              hipStream_t stream)
{
    char* ws = (char*)d_ws;
    const size_t MiB = 1048576;

    bf16*  xn  = (bf16*)(ws);                    // [ 0, 4): (2048,1024) ln1 out
    bf16*  xz  = (bf16*)(ws +  4 * MiB);         // [ 4,20): (2048,4096) in_proj out
    bf16*  uc  = (bf16*)(ws + 20 * MiB);         // [20,28): (2048,2048) conv+silu out
    bf16*  dbc = (bf16*)(ws + 28 * MiB);         // [28,28.4): (2048,96)
    bf16*  dlb = (bf16*)(ws + 28 * MiB + 524288);// [28.5,36.5): delta; scan writes y in-place
    bf16*  yb  = dlb;                            //   (element-aliased, safe per-row)
    float* hb  = (float*)(ws);                   // [ 0, 8): f32 resid (xn/xz dead at step 7)
    float* xpp = (float*)(ws);                   // [ 0, 3): x_proj split-K partials (xn dead)
    float2* carry = (float2*)d_out;              // 8 MiB scratch; step 10 fully overwrites
    bf16*  hn  = (bf16*)(ws +  8 * MiB);         // [ 8,12): ln2 out (over dead xz)
    bf16*  gb  = (bf16*)(ws + 12 * MiB);         // [12,20): mlp1 out (over dead xz)
    unsigned short* cvt = (unsigned short*)(ws + 37 * MiB);  // [37, 61.8): bf16 inputs

    const float* xf     = (const float*)d_in[0];
    const float* A_logf = (const float*)d_in[9];
    const float* Dpf    = (const float*)d_in[10];

    const bf16* in_proj_w  = (const bf16*)(cvt + 2099200);
    const bf16* conv_w     = (const bf16*)(cvt + 6293504);
    const bf16* conv_b     = (const bf16*)(cvt + 6301696);
    const bf16* x_proj_w   = (const bf16*)(cvt + 6303744);
    const bf16* dt_proj_w  = (const bf16*)(cvt + 6500352);
    const bf16* dt_proj_b  = (const bf16*)(cvt + 6631424);
    const bf16* out_proj_w = (const bf16*)(cvt + 6668288);
    const bf16* ln2_w      = (const bf16*)(cvt + 8765440);
    const bf16* ln2_b      = (const bf16*)(cvt + 8766464);
    const bf16* mlp_w1     = (const bf16*)(cvt + 8767488);
    const bf16* mlp_b1     = (const bf16*)(cvt + 10864640);
    const bf16* mlp_w2     = (const bf16*)(cvt + 10866688);
    const bf16* mlp_b2     = (const bf16*)(cvt + 12963840);

    // 0+1. fused: weight conversion fp32->bf16 (x skipped) + LN1
    Ptrs ptrs;
    for (int i = 0; i < 18; ++i) ptrs.p[i] = d_in[i];
    convert_ln1_kernel<<<7355, 256, 0, stream>>>(ptrs, cvt, xn);

    // 2. in_proj: (2048,4096,K=1024)  128x128, 512 blocks (2/CU)
    gemm_as<128, 128, 0, false, bf16, bf16><<<dim3(32, 16), 256, 0, stream>>>(
        xn, 1024, in_proj_w, 1024, xz, 4096, nullptr, (const bf16*)nullptr, 2048, 4096, 1024);
    // 3. depthwise causal conv + bias + silu -> uc (short8-vectorized)
    conv_silu_kernel<<<2048, 256, 0, stream>>>(xz, conv_w, conv_b, uc);
    // 4. x_proj split-K=4: (2048,96,K=2048) -> fp32 partials -> bf16 dbc
    gemm_xproj_sk<<<dim3(2, 32, 4), 256, 0, stream>>>(uc, x_proj_w, xpp);
    xproj_reduce<<<768, 256, 0, stream>>>(xpp, dbc);
    // 5. dt_proj + softplus: (2048,2048,K=64)  64x64, 1024 blocks (4/CU)
    gemm_as<64, 64, 2, false, bf16, bf16><<<dim3(32, 32), 256, 0, stream>>>(
        dbc, 96, dt_proj_w, 64, dlb, 2048, dt_proj_b, (const bf16*)nullptr, 2048, 2048, 64);
    // 6. selective scan v6: n-vectorized chunked (16 chunks of 64 steps)
    scan_carry_kernel<<<dim3(16, 2, 16), 128, 0, stream>>>(dlb, uc, dbc, A_logf, carry);
    scan_combine_kernel<<<256, 256, 0, stream>>>(carry);
    scan_apply_kernel<<<dim3(16, 2, 16), 128, 0, stream>>>(
        dlb, uc, dbc, xz, A_logf, Dpf, carry, yb);
    // 7. out_proj + residual x (fp32): (2048,1024,K=2048)  64x64, 512 blocks
    gemm_as<64, 64, 0, false, float, float><<<dim3(16, 32), 256, 0, stream>>>(
        yb, 2048, out_proj_w, 2048, hb, 1024, nullptr, xf, 2048, 1024, 2048);
    // 8. LN2
    ln_kernel<float><<<2048, 256, 0, stream>>>(hb, ln2_w, ln2_b, hn);
    // 9. MLP1 + gelu: (2048,2048,K=1024)  128x64 tile, 512 blocks (2/CU)
    gemm_as<128, 64, 1, false, bf16, bf16><<<dim3(32, 16), 256, 0, stream>>>(
        hn, 1024, mlp_w1, 1024, gb, 2048, mlp_b1, (const bf16*)nullptr, 2048, 2048, 1024);
    // 10. MLP2 + bias + residual h -> d_out (fp32): 64x64, 512 blocks
    //     (fully overwrites d_out, retiring the carry scratch)
    gemm_as<64, 64, 0, false, float, float><<<dim3(16, 32), 256, 0, stream>>>(
        gb, 2048, mlp_w2, 2048, (float*)d_out, 1024, mlp_b2, hb, 2048, 1024, 2048);
}

// Round 11
// 318.391 us; speedup vs baseline: 1.1658x; 1.0281x over previous
//
#include <hip/hip_runtime.h>
#include <hip/hip_bf16.h>
#include <math.h>

typedef __hip_bfloat16 bf16;
typedef __attribute__((ext_vector_type(8))) short bf16x8;
typedef __attribute__((ext_vector_type(4))) float f32x4;

__device__ __forceinline__ float b2f(bf16 x) { return __bfloat162float(x); }
__device__ __forceinline__ float us2f(unsigned short u) {
    return __uint_as_float(((unsigned int)u) << 16);
}
__device__ __forceinline__ unsigned short f2us(float f) {
    bf16 t = __float2bfloat16(f);
    return *reinterpret_cast<unsigned short*>(&t);
}
__device__ __forceinline__ float scrub(float v) {
    return (v == v && fabsf(v) < 3.0e38f) ? v : 0.f;
}
__device__ __forceinline__ float to_float(float x) { return x; }
__device__ __forceinline__ float to_float(bf16 x) { return __bfloat162float(x); }
__device__ __forceinline__ void store_out(float* p, float v) { *p = v; }
__device__ __forceinline__ void store_out(bf16* p, float v) { *p = __float2bfloat16(v); }

// async global->LDS, 16 B per lane; LDS dest = wave-uniform base + lane*16
__device__ __forceinline__ void cp16(const void* g, void* l) {
    __builtin_amdgcn_global_load_lds(
        (const __attribute__((address_space(1))) unsigned int*)g,
        (__attribute__((address_space(3))) unsigned int*)l, 16, 0, 0);
}

// ---------------------------------------------------------------------------
// Fused: weight conversion fp32->bf16 (x skipped) + LayerNorm-1 over x.
// ---------------------------------------------------------------------------
struct Ptrs { const void* p[18]; };

__constant__ __device__ const long TOFF[19] = {
    0,         2097152,  2098176,  2099200,  6293504,  6301696,  6303744,
    6500352,   6631424,  6633472,  6666240,  6668288,  8765440,  8766464,
    8767488,   10864640, 10866688, 12963840, 12964864};

__global__ __launch_bounds__(256) void convert_ln1_kernel(
    Ptrs ptrs, unsigned short* __restrict__ dst, bf16* __restrict__ out)
{
    __shared__ float red[8];
    if (blockIdx.x < 5307) {
        const long g = 262144 + (long)blockIdx.x * 256 + threadIdx.x;
        if (g >= 1620608) return;            // 12,964,864 / 8
        const long e0 = g * 8;
        int t = 1;                           // e0 >= TOFF[1] always here
        #pragma unroll
        for (int i = 2; i < 18; ++i) t += (e0 >= TOFF[i]) ? 1 : 0;
        const long local = e0 - TOFF[t];
        const float4* ps = (const float4*)((const float*)ptrs.p[t] + local);
        const float4 a = ps[0], b = ps[1];
        ushort4 o0, o1;
        o0.x = f2us(a.x); o0.y = f2us(a.y); o0.z = f2us(a.z); o0.w = f2us(a.w);
        o1.x = f2us(b.x); o1.y = f2us(b.y); o1.z = f2us(b.z); o1.w = f2us(b.w);
        *(ushort4*)(dst + e0)     = o0;
        *(ushort4*)(dst + e0 + 4) = o1;
        return;
    }
    // ---- LN1: one block per row, 256 threads x 4 elems, fp32 weights ----
    const int row = blockIdx.x - 5307;
    const int tid = threadIdx.x;
    const float* xf = (const float*)ptrs.p[0];
    const float4 raw = ((const float4*)(xf + (long)row * 1024))[tid];
    float v[4] = {raw.x, raw.y, raw.z, raw.w};
    float s  = v[0] + v[1] + v[2] + v[3];
    float s2 = v[0]*v[0] + v[1]*v[1] + v[2]*v[2] + v[3]*v[3];
    #pragma unroll
    for (int o = 32; o > 0; o >>= 1) {
        s  += __shfl_xor(s, o);
        s2 += __shfl_xor(s2, o);
    }
    if ((tid & 63) == 0) { red[tid >> 6] = s; red[4 + (tid >> 6)] = s2; }
    __syncthreads();
    s  = red[0] + red[1] + red[2] + red[3];
    s2 = red[4] + red[5] + red[6] + red[7];
    const float mu  = s * (1.f / 1024.f);
    const float var = fmaxf(s2 * (1.f / 1024.f) - mu * mu, 0.f);
    const float rs  = rsqrtf(var + 1e-5f);
    const float4 w4 = ((const float4*)ptrs.p[1])[tid];
    const float4 b4 = ((const float4*)ptrs.p[2])[tid];
    ushort4 o;
    o.x = f2us((v[0] - mu) * rs * w4.x + b4.x);
    o.y = f2us((v[1] - mu) * rs * w4.y + b4.y);
    o.z = f2us((v[2] - mu) * rs * w4.z + b4.z);
    o.w = f2us((v[3] - mu) * rs * w4.w + b4.w);
    ((ushort4*)((unsigned short*)out + (long)row * 1024))[tid] = o;
}

// ---------------------------------------------------------------------------
// LayerNorm (generic, bf16 weights): used for LN2 over fp32 residual.
// ---------------------------------------------------------------------------
template <typename TIN>
__global__ __launch_bounds__(256) void ln_kernel(
    const TIN* __restrict__ in, const bf16* __restrict__ gw,
    const bf16* __restrict__ gb, bf16* __restrict__ out)
{
    const int row = blockIdx.x;
    const int tid = threadIdx.x;
    float v[4];
    if constexpr (sizeof(TIN) == 2) {
        ushort4 raw = ((const ushort4*)((const unsigned short*)in + (long)row * 1024))[tid];
        v[0] = us2f(raw.x); v[1] = us2f(raw.y); v[2] = us2f(raw.z); v[3] = us2f(raw.w);
    } else {
        float4 raw = ((const float4*)((const float*)in + (long)row * 1024))[tid];
        v[0] = raw.x; v[1] = raw.y; v[2] = raw.z; v[3] = raw.w;
    }
    float s  = v[0] + v[1] + v[2] + v[3];
    float s2 = v[0]*v[0] + v[1]*v[1] + v[2]*v[2] + v[3]*v[3];
    #pragma unroll
    for (int o = 32; o > 0; o >>= 1) {
        s  += __shfl_xor(s, o);
        s2 += __shfl_xor(s2, o);
    }
    __shared__ float red[8];
    if ((tid & 63) == 0) { red[tid >> 6] = s; red[4 + (tid >> 6)] = s2; }
    __syncthreads();
    s  = red[0] + red[1] + red[2] + red[3];
    s2 = red[4] + red[5] + red[6] + red[7];
    const float mu  = s * (1.f / 1024.f);
    const float var = fmaxf(s2 * (1.f / 1024.f) - mu * mu, 0.f);
    const float rs  = rsqrtf(var + 1e-5f);
    const int c0 = tid * 4;
    ushort4 o;
    o.x = f2us((v[0] - mu) * rs * b2f(gw[c0 + 0]) + b2f(gb[c0 + 0]));
    o.y = f2us((v[1] - mu) * rs * b2f(gw[c0 + 1]) + b2f(gb[c0 + 1]));
    o.z = f2us((v[2] - mu) * rs * b2f(gw[c0 + 2]) + b2f(gb[c0 + 2]));
    o.w = f2us((v[3] - mu) * rs * b2f(gw[c0 + 3]) + b2f(gb[c0 + 3]));
    ((ushort4*)((unsigned short*)out + (long)row * 1024))[tid] = o;
}

// ---------------------------------------------------------------------------
// GEMM v2 (m97-style): C[M,N] = act(A[M,K] @ Bw[N,K]^T + bias) + res.
// ---------------------------------------------------------------------------
template <int BM, int BN, int ACT, bool NG, typename TOUT, typename TRES>
__global__ __launch_bounds__(256) void gemm_as(
    const bf16* __restrict__ A, int lda,
    const bf16* __restrict__ Bw, int ldb,
    TOUT* __restrict__ C, int ldc,
    const bf16* __restrict__ bias,
    const TRES* __restrict__ res,
    int M, int N, int K)
{
    constexpr int AI = BM / 32;
    constexpr int BJ = BN / 32;
    __shared__ __align__(16) short As[BM * 64];
    __shared__ __align__(16) short Bs[BN * 64];
    const int tid  = threadIdx.x;
    const int lane = tid & 63;
    const int wv   = tid >> 6;
    const int m0 = blockIdx.y * BM;
    const int n0 = blockIdx.x * BN;
    const int wm = (wv >> 1) * (BM / 2);
    const int wn = (wv & 1) * (BN / 2);
    const int lr = lane & 15;
    const int lq = lane >> 4;
    const int grow = lane >> 3;         // row 0..7 within an 8-row group
    const int gcol = (lane & 7) * 8;    // 16B chunk (shorts)

    if (NG) {
        const int z0 = (N - n0) * 64;
        uint4 z; z.x = z.y = z.z = z.w = 0;
        for (int s = z0 + tid * 8; s < BN * 64; s += 2048)
            *(uint4*)&Bs[s] = z;
    }

    f32x4 acc[AI][BJ] = {};

    for (int k0 = 0; k0 < K; k0 += 64) {
        #pragma unroll
        for (int g = 0; g < BM / 32; ++g) {
            const int gg = g * 4 + wv;   // wave-uniform 8-row group
            cp16(A + (long)(m0 + gg * 8 + grow) * lda + k0 + gcol, &As[gg * 512]);
        }
        #pragma unroll
        for (int g = 0; g < BN / 32; ++g) {
            const int gg = g * 4 + wv;
            if (!NG || n0 + gg * 8 < N)
                cp16(Bw + (long)(n0 + gg * 8 + grow) * ldb + k0 + gcol, &Bs[gg * 512]);
        }
        __syncthreads();

        #pragma unroll
        for (int kk = 0; kk < 2; ++kk) {
            bf16x8 af[AI], bfr[BJ];
            #pragma unroll
            for (int i = 0; i < AI; ++i)
                af[i] = *(const bf16x8*)&As[(wm + i * 16 + lr) * 64 + kk * 32 + lq * 8];
            #pragma unroll
            for (int j = 0; j < BJ; ++j)
                bfr[j] = *(const bf16x8*)&Bs[(wn + j * 16 + lr) * 64 + kk * 32 + lq * 8];
            #pragma unroll
            for (int i = 0; i < AI; ++i)
                #pragma unroll
                for (int j = 0; j < BJ; ++j)
                    acc[i][j] = __builtin_amdgcn_mfma_f32_16x16x32_bf16(
                        af[i], bfr[j], acc[i][j], 0, 0, 0);
        }
        __syncthreads();
    }

    #pragma unroll
    for (int j = 0; j < BJ; ++j) {
        const int col = n0 + wn + j * 16 + lr;
        if (col >= N) continue;
        const float bv = bias ? b2f(bias[col]) : 0.f;
        #pragma unroll
        for (int i = 0; i < AI; ++i) {
            const int r0 = m0 + wm + i * 16 + lq * 4;
            #pragma unroll
            for (int r = 0; r < 4; ++r) {
                const long row = r0 + r;
                float v = acc[i][j][r] + bv;
                if (ACT == 1) v = 0.5f * v * (1.f + erff(v * 0.70710678118f));
                if (ACT == 2) v = (v > 20.f) ? v : __logf(1.f + __expf(v));
                if (res) v += to_float(res[row * (long)ldc + col]);
                store_out(&C[row * (long)ldc + col], scrub(v));
            }
        }
    }
}

// ---------------------------------------------------------------------------
// x_proj split-K: (M=2048, N=96, K=2048), 4 K-ranges, fp32 partials + reduce.
// ---------------------------------------------------------------------------
__global__ __launch_bounds__(256) void gemm_xproj_sk(
    const bf16* __restrict__ A,      // uc (2048, 2048)
    const bf16* __restrict__ Bw,     // x_proj_w (96, 2048)
    float* __restrict__ P)           // (4, 2048, 96) partials
{
    constexpr int N = 96;
    __shared__ __align__(16) short As[64 * 64];
    __shared__ __align__(16) short Bs[64 * 64];
    const int tid  = threadIdx.x;
    const int lane = tid & 63;
    const int wv   = tid >> 6;
    const int m0 = blockIdx.y * 64;
    const int n0 = blockIdx.x * 64;
    const int kz = blockIdx.z;           // 0..3
    const int wm = (wv >> 1) * 32;
    const int wn = (wv & 1) * 32;
    const int lr = lane & 15;
    const int lq = lane >> 4;
    const int grow = lane >> 3;
    const int gcol = (lane & 7) * 8;

    {   // zero OOB B rows
        const int z0 = (N - n0) * 64;
        uint4 z; z.x = z.y = z.z = z.w = 0;
        for (int s = z0 + tid * 8; s < 64 * 64; s += 2048)
            *(uint4*)&Bs[s] = z;
    }

    f32x4 acc[2][2] = {};
    const int kend = kz * 512 + 512;
    for (int k0 = kz * 512; k0 < kend; k0 += 64) {
        #pragma unroll
        for (int g = 0; g < 2; ++g) {
            const int gg = g * 4 + wv;
            cp16(A + (long)(m0 + gg * 8 + grow) * 2048 + k0 + gcol, &As[gg * 512]);
        }
        #pragma unroll
        for (int g = 0; g < 2; ++g) {
            const int gg = g * 4 + wv;
            if (n0 + gg * 8 < N)
                cp16(Bw + (long)(n0 + gg * 8 + grow) * 2048 + k0 + gcol, &Bs[gg * 512]);
        }
        __syncthreads();
        #pragma unroll
        for (int kk = 0; kk < 2; ++kk) {
            bf16x8 af[2], bfr[2];
            #pragma unroll
            for (int i = 0; i < 2; ++i)
                af[i] = *(const bf16x8*)&As[(wm + i * 16 + lr) * 64 + kk * 32 + lq * 8];
            #pragma unroll
            for (int j = 0; j < 2; ++j)
                bfr[j] = *(const bf16x8*)&Bs[(wn + j * 16 + lr) * 64 + kk * 32 + lq * 8];
            #pragma unroll
            for (int i = 0; i < 2; ++i)
                #pragma unroll
                for (int j = 0; j < 2; ++j)
                    acc[i][j] = __builtin_amdgcn_mfma_f32_16x16x32_bf16(
                        af[i], bfr[j], acc[i][j], 0, 0, 0);
        }
        __syncthreads();
    }

    float* Pz = P + (long)kz * (2048 * 96);
    #pragma unroll
    for (int j = 0; j < 2; ++j) {
        const int col = n0 + wn + j * 16 + lr;
        if (col >= N) continue;
        #pragma unroll
        for (int i = 0; i < 2; ++i) {
            const int r0 = m0 + wm + i * 16 + lq * 4;
            #pragma unroll
            for (int r = 0; r < 4; ++r)
                Pz[(long)(r0 + r) * 96 + col] = acc[i][j][r];
        }
    }
}

__global__ __launch_bounds__(256) void xproj_reduce(
    const float* __restrict__ P, bf16* __restrict__ dbc)
{
    const int i = blockIdx.x * 256 + threadIdx.x;   // < 196608
    const float s = P[i] + P[i + 196608] + P[i + 2 * 196608] + P[i + 3 * 196608];
    dbc[i] = __float2bfloat16(scrub(s));
}

// ---------------------------------------------------------------------------
// Depthwise causal conv (window 4) + bias + silu, short8-vectorized.
// ---------------------------------------------------------------------------
__global__ __launch_bounds__(256) void conv_silu_kernel(
    const bf16* __restrict__ xz, const bf16* __restrict__ cw,
    const bf16* __restrict__ cb, bf16* __restrict__ uc)
{
    const int gid = blockIdx.x * 256 + threadIdx.x;
    const int dc  = (gid & 255) * 8;
    const int row = gid >> 8;
    const int t   = row & 1023;
    const bf16x8 w0 = *(const bf16x8*)(cw + dc * 4);
    const bf16x8 w1 = *(const bf16x8*)(cw + dc * 4 + 8);
    const bf16x8 w2 = *(const bf16x8*)(cw + dc * 4 + 16);
    const bf16x8 w3 = *(const bf16x8*)(cw + dc * 4 + 24);
    const bf16x8 bv = *(const bf16x8*)(cb + dc);
    float wf[32];
    #pragma unroll
    for (int k = 0; k < 8; ++k) {
        wf[k]      = us2f((unsigned short)w0[k]);
        wf[8 + k]  = us2f((unsigned short)w1[k]);
        wf[16 + k] = us2f((unsigned short)w2[k]);
        wf[24 + k] = us2f((unsigned short)w3[k]);
    }
    float acc[8];
    #pragma unroll
    for (int i = 0; i < 8; ++i) acc[i] = us2f((unsigned short)bv[i]);
    #pragma unroll
    for (int j = 0; j < 4; ++j) {
        const int tt = t - 3 + j;
        if (tt < 0) continue;
        const bf16x8 xv = *(const bf16x8*)(xz + (long)(row - 3 + j) * 4096 + dc);
        #pragma unroll
        for (int i = 0; i < 8; ++i)
            acc[i] += wf[i * 4 + j] * us2f((unsigned short)xv[i]);
    }
    bf16x8 o;
    #pragma unroll
    for (int i = 0; i < 8; ++i) {
        const float sg = 1.f / (1.f + __expf(-acc[i]));
        o[i] = (short)f2us(acc[i] * sg);
    }
    *(bf16x8*)(uc + (long)row * 2048 + dc) = o;
}

// ---------------------------------------------------------------------------
// Selective scan v6.1 -- n-vectorized chunked scan, occupancy-tuned.
// R9 measurement: v6 trio ~75us total (by subtraction vs R3's 326 baseline)
// -- each pass 2x faster than monolithic layout but at 1 wave/SIMD the
// LDS-read latency per t-step is fully exposed (R7's chunked version at
// 12 waves/CU showed VALUBusy only 43%, so not issue-saturated).
// v6.1: CS=32-step chunks, NC=32 -> grid 1024 blocks = 4 blocks/CU =
// 2 waves/SIMD (apply LDS 28KB allows 5/CU), serial chain halved.
// Carry A_prod via exp(An * sum(dt)) instead of per-step product
// (exact identity; kills 16 muls/step in the carry pass).
// Carry = 16 MiB -> ws+64MiB (ws is 256 MiB per harness fill evidence;
// region is beyond cvt end at 61.8 MiB, untouched by anything else).
// ---------------------------------------------------------------------------
__global__ __launch_bounds__(128) void scan_carry_kernel(
    const bf16* __restrict__ delta,    // (B*L, 2048)
    const bf16* __restrict__ uc,       // (B*L, 2048)
    const bf16* __restrict__ dbc,      // (B*L, 96): dt | B | C
    const float* __restrict__ A_log,   // (2048, 16) fp32
    float2* __restrict__ carry)        // (B, 32, 2048, 16): {A_prod, h_local}
{
    const int d0  = blockIdx.x * 128;
    const int b   = blockIdx.y;
    const int c   = blockIdx.z;        // 0..31
    const int tid = threadIdx.x;       // 0..127
    const int lane = tid & 63;
    const int wv   = tid >> 6;         // 0..1
    const int d    = d0 + tid;

    __shared__ __align__(16) unsigned short sDT[32][128];  // 8 KB
    __shared__ __align__(16) unsigned short sU [32][128];  // 8 KB
    __shared__ __align__(16) float sB[32][16];             // 2 KB

    float An[16];
    {
        const float4* ap = (const float4*)(A_log + (long)d * 16);
        #pragma unroll
        for (int q = 0; q < 4; ++q) {
            const float4 a4 = ap[q];
            An[q*4+0] = -expf(a4.x); An[q*4+1] = -expf(a4.y);
            An[q*4+2] = -expf(a4.z); An[q*4+3] = -expf(a4.w);
        }
    }

    const long r0 = (long)b * 1024 + c * 32;

    // stage dt,u: per cp16 a wave moves 4 rows (16 lanes x 16B per row)
    const int srow = lane >> 4;
    const int scol = (lane & 15) * 8;
    #pragma unroll
    for (int g = 0; g < 4; ++g) {
        const int grp = g * 2 + wv;           // 0..7, 4 rows each
        const long r = r0 + grp * 4 + srow;
        cp16((const unsigned short*)delta + r * 2048 + d0 + scol, &sDT[grp * 4][0]);
        cp16((const unsigned short*)uc    + r * 2048 + d0 + scol, &sU [grp * 4][0]);
    }
    // stage B (32 rows x 16 bf16) -> f32: 32x4 quads = 128, one per thread
    {
        const int row = tid >> 2, quad = tid & 3;
        const ushort4 v = *(const ushort4*)((const unsigned short*)dbc
                              + (r0 + row) * 96 + 64 + quad * 4);
        sB[row][quad*4+0] = us2f(v.x); sB[row][quad*4+1] = us2f(v.y);
        sB[row][quad*4+2] = us2f(v.z); sB[row][quad*4+3] = us2f(v.w);
    }

    float h[16];
    #pragma unroll
    for (int n = 0; n < 16; ++n) h[n] = 0.f;
    float Sdt = 0.f;
    __syncthreads();   // drains vmcnt (cp16) before LDS reads

    #pragma unroll 2
    for (int t = 0; t < 32; ++t) {
        const float dt = us2f(sDT[t][tid]);
        const float u  = us2f(sU [t][tid]);
        const float s  = dt * u;
        Sdt += dt;
        const float4 b0 = *(const float4*)&sB[t][0];
        const float4 b1 = *(const float4*)&sB[t][4];
        const float4 b2 = *(const float4*)&sB[t][8];
        const float4 b3 = *(const float4*)&sB[t][12];
        const float Bv[16] = {b0.x,b0.y,b0.z,b0.w, b1.x,b1.y,b1.z,b1.w,
                              b2.x,b2.y,b2.z,b2.w, b3.x,b3.y,b3.z,b3.w};
        #pragma unroll
        for (int n = 0; n < 16; ++n) {
            const float a = __expf(dt * An[n]);
            h[n] = a * h[n] + s * Bv[n];
        }
    }
    float2* cp = carry + ((long)(b * 32 + c) * 32768 + (long)d * 16);
    #pragma unroll
    for (int n = 0; n < 16; ++n)
        cp[n] = float2{__expf(An[n] * Sdt), h[n]};
}

__global__ __launch_bounds__(256) void scan_combine_kernel(float2* __restrict__ carry)
{
    const int gid = blockIdx.x * 256 + threadIdx.x;   // 65536 chains
    const int b   = gid >> 15;
    const int rem = gid & 32767;                      // d*16 + n
    float h = 0.f;
    #pragma unroll
    for (int c = 0; c < 32; ++c) {
        float2* p = &carry[((long)b * 32 + c) * 32768 + rem];
        const float2 AB = *p;
        ((float*)p)[0] = h;          // h0 entering chunk c (in-place over A)
        h = AB.x * h + AB.y;
    }
}

__global__ __launch_bounds__(128) void scan_apply_kernel(
    const bf16* __restrict__ delta,    // (B*L, 2048)
    const bf16* __restrict__ uc,       // (B*L, 2048)
    const bf16* __restrict__ dbc,      // (B*L, 96): dt | B | C
    const bf16* __restrict__ xz,       // (B*L, 4096): z at cols 2048+d
    const float* __restrict__ A_log,   // (2048, 16) fp32
    const float* __restrict__ Dp,      // (2048)     fp32
    const float2* __restrict__ carry,  // h0 in .x after combine
    bf16* __restrict__ y)              // (B*L, 2048)
{
    const int d0  = blockIdx.x * 128;
    const int b   = blockIdx.y;
    const int c   = blockIdx.z;        // 0..31
    const int tid = threadIdx.x;
    const int lane = tid & 63;
    const int wv   = tid >> 6;
    const int d    = d0 + tid;

    __shared__ __align__(16) unsigned short sDT[32][128];  // 8 KB
    __shared__ __align__(16) unsigned short sU [32][128];  // 8 KB
    __shared__ __align__(16) unsigned short sZ [32][128];  // 8 KB
    __shared__ __align__(16) float sB[32][16];             // 2 KB
    __shared__ __align__(16) float sC[32][16];             // 2 KB

    float An[16];
    {
        const float4* ap = (const float4*)(A_log + (long)d * 16);
        #pragma unroll
        for (int q = 0; q < 4; ++q) {
            const float4 a4 = ap[q];
            An[q*4+0] = -expf(a4.x); An[q*4+1] = -expf(a4.y);
            An[q*4+2] = -expf(a4.z); An[q*4+3] = -expf(a4.w);
        }
    }
    const float Dd = Dp[d];

    const long r0 = (long)b * 1024 + c * 32;

    const int srow = lane >> 4;
    const int scol = (lane & 15) * 8;
    #pragma unroll
    for (int g = 0; g < 4; ++g) {
        const int grp = g * 2 + wv;           // 0..7, 4 rows each
        const long r = r0 + grp * 4 + srow;
        cp16((const unsigned short*)delta + r * 2048 + d0 + scol, &sDT[grp * 4][0]);
        cp16((const unsigned short*)uc    + r * 2048 + d0 + scol, &sU [grp * 4][0]);
        cp16((const unsigned short*)xz    + r * 4096 + 2048 + d0 + scol, &sZ[grp * 4][0]);
    }
    // stage B,C (32 rows x 32 bf16) -> f32: 32x8 quads = 256 entries
    #pragma unroll
    for (int k = 0; k < 2; ++k) {
        const int q = tid + k * 128;          // 0..255
        const int row = q >> 3, quad = q & 7;
        const ushort4 v = *(const ushort4*)((const unsigned short*)dbc
                              + (r0 + row) * 96 + 64 + quad * 4);
        float* dst = (quad < 4) ? &sB[row][quad * 4] : &sC[row][(quad - 4) * 4];
        dst[0] = us2f(v.x); dst[1] = us2f(v.y); dst[2] = us2f(v.z); dst[3] = us2f(v.w);
    }

    // h0: 16 consecutive float2 = 8 float4 per lane, contiguous 128B
    float h[16];
    {
        const float4* hp = (const float4*)(carry + ((long)(b * 32 + c) * 32768
                                                    + (long)d * 16));
        #pragma unroll
        for (int k = 0; k < 8; ++k) {
            const float4 v = hp[k];
            h[2*k]   = v.x;    // .x of float2 pair 2k
            h[2*k+1] = v.z;    // .x of float2 pair 2k+1
        }
    }
    __syncthreads();

    unsigned short* yp = (unsigned short*)y + r0 * 2048 + d;

    #pragma unroll 2
    for (int t = 0; t < 32; ++t) {
        const float dt = us2f(sDT[t][tid]);
        const float u  = us2f(sU [t][tid]);
        const float zz = us2f(sZ [t][tid]);
        const float s  = dt * u;
        const float4 b0 = *(const float4*)&sB[t][0];
        const float4 b1 = *(const float4*)&sB[t][4];
        const float4 b2 = *(const float4*)&sB[t][8];
        const float4 b3 = *(const float4*)&sB[t][12];
        const float4 c0 = *(const float4*)&sC[t][0];
        const float4 c1 = *(const float4*)&sC[t][4];
        const float4 c2 = *(const float4*)&sC[t][8];
        const float4 c3 = *(const float4*)&sC[t][12];
        const float Bv[16] = {b0.x,b0.y,b0.z,b0.w, b1.x,b1.y,b1.z,b1.w,
                              b2.x,b2.y,b2.z,b2.w, b3.x,b3.y,b3.z,b3.w};
        const float Cv[16] = {c0.x,c0.y,c0.z,c0.w, c1.x,c1.y,c1.z,c1.w,
                              c2.x,c2.y,c2.z,c2.w, c3.x,c3.y,c3.z,c3.w};
        float y0 = 0.f, y1 = 0.f, y2 = 0.f, y3 = 0.f;
        #pragma unroll
        for (int n = 0; n < 4; ++n) {
            const float a = __expf(dt * An[n]);
            h[n] = a * h[n] + s * Bv[n];
            y0 += h[n] * Cv[n];
        }
        #pragma unroll
        for (int n = 4; n < 8; ++n) {
            const float a = __expf(dt * An[n]);
            h[n] = a * h[n] + s * Bv[n];
            y1 += h[n] * Cv[n];
        }
        #pragma unroll
        for (int n = 8; n < 12; ++n) {
            const float a = __expf(dt * An[n]);
            h[n] = a * h[n] + s * Bv[n];
            y2 += h[n] * Cv[n];
        }
        #pragma unroll
        for (int n = 12; n < 16; ++n) {
            const float a = __expf(dt * An[n]);
            h[n] = a * h[n] + s * Bv[n];
            y3 += h[n] * Cv[n];
        }
        const float ys  = (y0 + y1) + (y2 + y3) + u * Dd;
        const float sil = zz / (1.f + __expf(-zz));
        yp[(long)t * 2048] = f2us(ys * sil);
    }
}

// ---------------------------------------------------------------------------
extern "C" void kernel_launch(void* const* d_in, const int* in_sizes, int n_in,
                              void* d_out, int out_size, void* d_ws, size_t ws_size,
                              hipStream_t stream)
{
    char* ws = (char*)d_ws;
    const size_t MiB = 1048576;

    bf16*  xn  = (bf16*)(ws);                    // [ 0, 4): (2048,1024) ln1 out
    bf16*  xz  = (bf16*)(ws +  4 * MiB);         // [ 4,20): (2048,4096) in_proj out
    bf16*  uc  = (bf16*)(ws + 20 * MiB);         // [20,28): (2048,2048) conv+silu out
    bf16*  dbc = (bf16*)(ws + 28 * MiB);         // [28,28.4): (2048,96)
    bf16*  dlb = (bf16*)(ws + 28 * MiB + 524288);// [28.5,36.5): delta; scan writes y in-place
    bf16*  yb  = dlb;                            //   (element-aliased, safe per-row)
    float* hb  = (float*)(ws);                   // [ 0, 8): f32 resid (xn/xz dead at step 7)
    float* xpp = (float*)(ws);                   // [ 0, 3): x_proj split-K partials (xn dead)
    float2* carry = (float2*)(ws + 64 * MiB);    // [64,80): 16 MiB scan carries
    bf16*  hn  = (bf16*)(ws +  8 * MiB);         // [ 8,12): ln2 out (over dead xz)
    bf16*  gb  = (bf16*)(ws + 12 * MiB);         // [12,20): mlp1 out (over dead xz)
    unsigned short* cvt = (unsigned short*)(ws + 37 * MiB);  // [37, 61.8): bf16 inputs

    const float* xf     = (const float*)d_in[0];
    const float* A_logf = (const float*)d_in[9];
    const float* Dpf    = (const float*)d_in[10];

    const bf16* in_proj_w  = (const bf16*)(cvt + 2099200);
    const bf16* conv_w     = (const bf16*)(cvt + 6293504);
    const bf16* conv_b     = (const bf16*)(cvt + 6301696);
    const bf16* x_proj_w   = (const bf16*)(cvt + 6303744);
    const bf16* dt_proj_w  = (const bf16*)(cvt + 6500352);
    const bf16* dt_proj_b  = (const bf16*)(cvt + 6631424);
    const bf16* out_proj_w = (const bf16*)(cvt + 6668288);
    const bf16* ln2_w      = (const bf16*)(cvt + 8765440);
    const bf16* ln2_b      = (const bf16*)(cvt + 8766464);
    const bf16* mlp_w1     = (const bf16*)(cvt + 8767488);
    const bf16* mlp_b1     = (const bf16*)(cvt + 10864640);
    const bf16* mlp_w2     = (const bf16*)(cvt + 10866688);
    const bf16* mlp_b2     = (const bf16*)(cvt + 12963840);

    // 0+1. fused: weight conversion fp32->bf16 (x skipped) + LN1
    Ptrs ptrs;
    for (int i = 0; i < 18; ++i) ptrs.p[i] = d_in[i];
    convert_ln1_kernel<<<7355, 256, 0, stream>>>(ptrs, cvt, xn);

    // 2. in_proj: (2048,4096,K=1024)  128x128, 512 blocks (2/CU)
    gemm_as<128, 128, 0, false, bf16, bf16><<<dim3(32, 16), 256, 0, stream>>>(
        xn, 1024, in_proj_w, 1024, xz, 4096, nullptr, (const bf16*)nullptr, 2048, 4096, 1024);
    // 3. depthwise causal conv + bias + silu -> uc (short8-vectorized)
    conv_silu_kernel<<<2048, 256, 0, stream>>>(xz, conv_w, conv_b, uc);
    // 4. x_proj split-K=4: (2048,96,K=2048) -> fp32 partials -> bf16 dbc
    gemm_xproj_sk<<<dim3(2, 32, 4), 256, 0, stream>>>(uc, x_proj_w, xpp);
    xproj_reduce<<<768, 256, 0, stream>>>(xpp, dbc);
    // 5. dt_proj + softplus: (2048,2048,K=64)  64x64, 1024 blocks (4/CU)
    gemm_as<64, 64, 2, false, bf16, bf16><<<dim3(32, 32), 256, 0, stream>>>(
        dbc, 96, dt_proj_w, 64, dlb, 2048, dt_proj_b, (const bf16*)nullptr, 2048, 2048, 64);
    // 6. selective scan v6.1: n-vectorized, 32 chunks of 32 steps
    //    (1024 blocks = 4/CU = 2 waves/SIMD for latency hiding)
    scan_carry_kernel<<<dim3(16, 2, 32), 128, 0, stream>>>(dlb, uc, dbc, A_logf, carry);
    scan_combine_kernel<<<256, 256, 0, stream>>>(carry);
    scan_apply_kernel<<<dim3(16, 2, 32), 128, 0, stream>>>(
        dlb, uc, dbc, xz, A_logf, Dpf, carry, yb);
    // 7. out_proj + residual x (fp32): (2048,1024,K=2048)  64x64, 512 blocks
    gemm_as<64, 64, 0, false, float, float><<<dim3(16, 32), 256, 0, stream>>>(
        yb, 2048, out_proj_w, 2048, hb, 1024, nullptr, xf, 2048, 1024, 2048);
    // 8. LN2
    ln_kernel<float><<<2048, 256, 0, stream>>>(hb, ln2_w, ln2_b, hn);
    // 9. MLP1 + gelu: (2048,2048,K=1024)  128x64 tile, 512 blocks (2/CU)
    gemm_as<128, 64, 1, false, bf16, bf16><<<dim3(32, 16), 256, 0, stream>>>(
        hn, 1024, mlp_w1, 1024, gb, 2048, mlp_b1, (const bf16*)nullptr, 2048, 2048, 1024);
    // 10. MLP2 + bias + residual h -> d_out (fp32): 64x64, 512 blocks
    gemm_as<64, 64, 0, false, float, float><<<dim3(16, 32), 256, 0, stream>>>(
        gb, 2048, mlp_w2, 2048, (float*)d_out, 1024, mlp_b2, hb, 2048, 1024, 2048);
}